// Round 12
// baseline (785.716 us; speedup 1.0000x reference)
//
#include <hip/hip_runtime.h>
#include <hip/hip_fp16.h>

// ---------------------------------------------------------------------------
// GGNNWithTopoAlpha  (B=4, N=2048, HD=256, E=4096, T=1024, 5 propag steps)
// Round 12: dispatch/round-trip reduction.
//  - split_h16 fused into gxgru epilogue (LDS bounce -> hbuf + hrm + hT),
//    removing 6 launches + 24MB/step h re-read. GRU math bit-identical.
//  - topo: Bcat=[B1^T|B2] concat buffer; qT = [pT|rT]*Bcat^T single K=3072
//    GEMM (drops qTf round-trip + 1 GEMM). mm_f16/split_t16 gain lda/ldb.
// step1 / adjacency path unchanged (at 2-barrier structural ceiling).
// ---------------------------------------------------------------------------

typedef __bf16 bf16x8 __attribute__((ext_vector_type(8)));
typedef _Float16 f16x8 __attribute__((ext_vector_type(8)));
typedef float f32x4 __attribute__((ext_vector_type(4)));

#define BM 128
#define BN 128
#define BK 16
#define LO_INV (1.f / 1024.f)

// ---- bf16 helpers (tier-2/3 fallback kernels only) ----
__device__ __forceinline__ unsigned short bf16rne(float x)
{
    unsigned u = __float_as_uint(x);
    return (unsigned short)((u + 0x7FFFu + ((u >> 16) & 1u)) >> 16);
}
__device__ __forceinline__ float bf2f(unsigned short h)
{
    return __uint_as_float((unsigned)h << 16);
}
__device__ __forceinline__ void split2(float x, unsigned short& hi, unsigned short& lo)
{
    hi = bf16rne(x);
    lo = bf16rne(x - bf2f(hi));
}

// ---- fp16 helpers (tier-1) ----
__device__ __forceinline__ unsigned short f16r(float x)
{
    return __half_as_ushort(__float2half(x));
}
__device__ __forceinline__ float f16f(unsigned short u)
{
    return __half2float(__ushort_as_half(u));
}
// 2-term fp16 split, lo pre-scaled by 2^10 (keeps residuals in normal range)
__device__ __forceinline__ void splitf(float x, unsigned short& hi, unsigned short& lo)
{
    hi = f16r(x);
    lo = f16r((x - f16f(hi)) * 1024.f);
}

__device__ __forceinline__ void gload_lds16(const unsigned short* g, unsigned short* l)
{
    __builtin_amdgcn_global_load_lds(
        (const __attribute__((address_space(1))) void*)g,
        (__attribute__((address_space(3))) void*)l, 16, 0, 0);
}

// ---------------------------------------------------------------------------
// 64x64 fp16 MFMA core: BK=64, 4 waves 2x2, XOR-swizzled LDS.
// SPLIT=0: C = Ah*Bh.  SPLIT=1: acc0 = Ah*Bh; acc1 = Al*Bh + Ah*Bl (lo x2^10).
// ld = row stride (elements) of the operand matrices.
// ---------------------------------------------------------------------------
__device__ __forceinline__ void stage2(const unsigned short* g, unsigned short* l, int ld)
{
    gload_lds16(g, l);
    gload_lds16(g + (size_t)32 * ld, l + 2048);
}

template<int SPLIT>
__device__ __forceinline__ void mm_loop64f(
    const unsigned short* ag0, const unsigned short* ag1,
    const unsigned short* bg0, const unsigned short* bg1,
    int K, int lda, int ldb, unsigned short* LDS, int tid,
    f32x4 (&acc0)[2][2], f32x4 (&acc1)[2][2])
{
    constexpr int NT = SPLIT ? 2 : 1;
    constexpr int TSZ = 4096;

    int lane = tid & 63, r16 = lane & 15, g = lane >> 4, s7 = r16 & 7;
    int wv = tid >> 6, wr = wv >> 1, wc = wv & 1;
    int arow = (wr * 32 + r16) * 128;
    int brow = (wc * 32 + r16) * 128;
    unsigned short* lA = LDS + (tid >> 6) * 512;
    unsigned short* lB = LDS + NT * TSZ + (tid >> 6) * 512;
    const char* Ab = (const char*)LDS;
    const char* Bb = (const char*)(LDS + NT * TSZ);

    for (int k0 = 0; k0 < K; k0 += 64) {
        stage2(ag0 + k0, lA, lda);
        if constexpr (SPLIT) stage2(ag1 + k0, lA + TSZ, lda);
        stage2(bg0 + k0, lB, ldb);
        if constexpr (SPLIT) stage2(bg1 + k0, lB + TSZ, ldb);
        __syncthreads();
#pragma unroll
        for (int ks = 0; ks < 2; ++ks) {
            int tt = ((ks * 4 + g) ^ s7) * 16;
            f16x8 a0[2], a1[2], b0[2], b1[2];
#pragma unroll
            for (int mi = 0; mi < 2; ++mi) {
                a0[mi] = *(const f16x8*)(Ab + arow + mi * 2048 + tt);
                if constexpr (SPLIT)
                    a1[mi] = *(const f16x8*)(Ab + TSZ * 2 + arow + mi * 2048 + tt);
            }
#pragma unroll
            for (int ni = 0; ni < 2; ++ni) {
                b0[ni] = *(const f16x8*)(Bb + brow + ni * 2048 + tt);
                if constexpr (SPLIT)
                    b1[ni] = *(const f16x8*)(Bb + TSZ * 2 + brow + ni * 2048 + tt);
            }
#pragma unroll
            for (int mi = 0; mi < 2; ++mi)
#pragma unroll
                for (int ni = 0; ni < 2; ++ni) {
                    if constexpr (SPLIT) {
                        acc1[mi][ni] = __builtin_amdgcn_mfma_f32_16x16x32_f16(
                            a1[mi], b0[ni], acc1[mi][ni], 0, 0, 0);
                        acc1[mi][ni] = __builtin_amdgcn_mfma_f32_16x16x32_f16(
                            a0[mi], b1[ni], acc1[mi][ni], 0, 0, 0);
                    }
                    acc0[mi][ni] = __builtin_amdgcn_mfma_f32_16x16x32_f16(
                        a0[mi], b0[ni], acc0[mi][ni], 0, 0, 0);
                }
        }
        __syncthreads();
    }
}

// Generic fp16 wrapper: 64x64 tiles + XCD-chunked swizzle; lda/ldb row strides.
template<int SPLIT, int OF16>
__global__ __launch_bounds__(256, 2) void mm_f16(
    const unsigned short* __restrict__ Ah, const unsigned short* __restrict__ Al,
    int lda,
    const unsigned short* __restrict__ Bh, const unsigned short* __restrict__ Bl,
    int ldb,
    int K, const float* __restrict__ bias, const float* __restrict__ Cacc,
    void* __restrict__ Cout, int ldc)
{
    constexpr int NT = SPLIT ? 2 : 1;
    __shared__ unsigned short LDS[2 * NT * 4096];
    int tid = threadIdx.x;

    unsigned nwg = gridDim.x * gridDim.y;
    unsigned lin = blockIdx.y * gridDim.x + blockIdx.x;
    unsigned wk = ((nwg & 7) == 0) ? (lin & 7) * (nwg >> 3) + (lin >> 3) : lin;
    unsigned bx = wk % gridDim.x, by = wk / gridDim.x;

    int m0 = by * 64, n0 = bx * 64;
    int rp = tid >> 3, sl8 = ((tid & 7) ^ (rp & 7)) * 8;
    const unsigned short* ag0 = Ah + (size_t)(m0 + rp) * lda + sl8;
    const unsigned short* ag1 = SPLIT ? Al + (size_t)(m0 + rp) * lda + sl8 : nullptr;
    const unsigned short* bg0 = Bh + (size_t)(n0 + rp) * ldb + sl8;
    const unsigned short* bg1 = SPLIT ? Bl + (size_t)(n0 + rp) * ldb + sl8 : nullptr;

    f32x4 acc0[2][2], acc1[2][2];
#pragma unroll
    for (int mi = 0; mi < 2; ++mi)
#pragma unroll
        for (int ni = 0; ni < 2; ++ni) {
            acc0[mi][ni] = (f32x4){0.f, 0.f, 0.f, 0.f};
            acc1[mi][ni] = (f32x4){0.f, 0.f, 0.f, 0.f};
        }

    mm_loop64f<SPLIT>(ag0, ag1, bg0, bg1, K, lda, ldb, LDS, tid, acc0, acc1);

    int lane = tid & 63, r16 = lane & 15, g = lane >> 4;
    int wv = tid >> 6, wr = wv >> 1, wc = wv & 1;
#pragma unroll
    for (int mi = 0; mi < 2; ++mi) {
#pragma unroll
        for (int ni = 0; ni < 2; ++ni) {
            int col = n0 + wc * 32 + ni * 16 + r16;
            float badd = bias ? bias[col] : 0.f;
#pragma unroll
            for (int j = 0; j < 4; ++j) {
                int row = m0 + wr * 32 + mi * 16 + g * 4 + j;
                float v = acc0[mi][ni][j] + badd;
                if (SPLIT) v += acc1[mi][ni][j] * LO_INV;
                if (Cacc) v += Cacc[(size_t)row * ldc + col];
                if (OF16)
                    ((unsigned short*)Cout)[(size_t)row * ldc + col] = f16r(v);
                else
                    ((float*)Cout)[(size_t)row * ldc + col] = v;
            }
        }
    }
}

// ---------------------------------------------------------------------------
// gxgru: fused gx GEMM (3P fp16, K=512) + GRU epilogue + h split outputs.
// W_ih pre-reordered t-block-major. After GRU math, h tile bounces through
// LDS and emits: hbuf (f32), hrm hi/lo (row-major fp16 2-term), hT hi/lo
// (transposed fp16 2-term) — replacing the per-step split_h16 launch.
// grid (4, 128) = 512 blocks, 64KB LDS. XCD-chunked swizzle.
// ---------------------------------------------------------------------------
__global__ __launch_bounds__(256, 2) void gxgru(
    const unsigned short* __restrict__ Xhi, const unsigned short* __restrict__ Xlo,
    const unsigned short* __restrict__ WihH, const unsigned short* __restrict__ WihL,
    const float* __restrict__ b_ih, const float* __restrict__ ghb,
    float* __restrict__ h,
    unsigned short* __restrict__ hrmh, unsigned short* __restrict__ hrml,
    unsigned short* __restrict__ hTh, unsigned short* __restrict__ hTl)
{
    __shared__ unsigned short LDS[32768];   // 64KB
    int tid = threadIdx.x;

    unsigned lin = blockIdx.y * 4 + blockIdx.x;
    unsigned wk = (lin & 7) * 64 + (lin >> 3);
    unsigned tb = wk & 3, by = wk >> 2;

    int m0 = by * 64;
    const int K = 512;
    int rp = tid >> 3, sl8 = ((tid & 7) ^ (rp & 7)) * 8;
    const unsigned short* ag0 = Xhi + (size_t)(m0 + rp) * K + sl8;
    const unsigned short* ag1 = Xlo + (size_t)(m0 + rp) * K + sl8;
    const unsigned short* bh0 = WihH + (size_t)(tb * 192 + rp) * K + sl8;
    const unsigned short* bl0 = WihL + (size_t)(tb * 192 + rp) * K + sl8;

    int lane = tid & 63, r16 = lane & 15, lg = lane >> 4, s7 = r16 & 7;
    int wv = tid >> 6, wr = wv >> 1, wc = wv & 1;
    int arow = (wr * 32 + r16) * 128;
    int brow = (wc * 32 + r16) * 128;
    unsigned short* lA = LDS + (tid >> 6) * 512;
    unsigned short* lB = LDS + 8192 + (tid >> 6) * 512;

    f32x4 acc0[3][2][2], acc1[3][2][2];
#pragma unroll
    for (int g = 0; g < 3; ++g)
#pragma unroll
        for (int mi = 0; mi < 2; ++mi)
#pragma unroll
            for (int ni = 0; ni < 2; ++ni) {
                acc0[g][mi][ni] = (f32x4){0.f, 0.f, 0.f, 0.f};
                acc1[g][mi][ni] = (f32x4){0.f, 0.f, 0.f, 0.f};
            }

    for (int k0 = 0; k0 < K; k0 += 64) {
        stage2(ag0 + k0, lA, K);
        stage2(ag1 + k0, lA + 4096, K);
#pragma unroll
        for (int g = 0; g < 3; ++g) {
            stage2(bh0 + (size_t)(g * 64) * K + k0, lB + g * 4096, K);
            stage2(bl0 + (size_t)(g * 64) * K + k0, lB + 12288 + g * 4096, K);
        }
        __syncthreads();
#pragma unroll
        for (int ks = 0; ks < 2; ++ks) {
            int tt = ((ks * 4 + lg) ^ s7) * 16;
            f16x8 a0[2], a1[2];
#pragma unroll
            for (int mi = 0; mi < 2; ++mi) {
                a0[mi] = *(const f16x8*)((const char*)LDS + arow + mi * 2048 + tt);
                a1[mi] = *(const f16x8*)((const char*)LDS + 8192 + arow + mi * 2048 + tt);
            }
#pragma unroll
            for (int g = 0; g < 3; ++g) {
                f16x8 b0[2], b1[2];
#pragma unroll
                for (int ni = 0; ni < 2; ++ni) {
                    b0[ni] = *(const f16x8*)((const char*)LDS + 16384 + g * 8192 +
                                             brow + ni * 2048 + tt);
                    b1[ni] = *(const f16x8*)((const char*)LDS + 40960 + g * 8192 +
                                             brow + ni * 2048 + tt);
                }
#pragma unroll
                for (int mi = 0; mi < 2; ++mi)
#pragma unroll
                    for (int ni = 0; ni < 2; ++ni) {
                        acc1[g][mi][ni] = __builtin_amdgcn_mfma_f32_16x16x32_f16(
                            a1[mi], b0[ni], acc1[g][mi][ni], 0, 0, 0);
                        acc1[g][mi][ni] = __builtin_amdgcn_mfma_f32_16x16x32_f16(
                            a0[mi], b1[ni], acc1[g][mi][ni], 0, 0, 0);
                        acc0[g][mi][ni] = __builtin_amdgcn_mfma_f32_16x16x32_f16(
                            a0[mi], b0[ni], acc0[g][mi][ni], 0, 0, 0);
                    }
            }
        }
        __syncthreads();
    }

    // ---- GRU epilogue (same math as r11) -> LDS tile T2[row64][t64] ----
    float* T2 = reinterpret_cast<float*>(LDS);   // 64*64 f32 = 64KB exactly
#pragma unroll
    for (int mi = 0; mi < 2; ++mi) {
#pragma unroll
        for (int ni = 0; ni < 2; ++ni) {
            int tl = wc * 32 + ni * 16 + r16;
            int t = tb * 64 + tl;
            float br = b_ih[t], bz = b_ih[256 + t], bn = b_ih[512 + t];
#pragma unroll
            for (int j = 0; j < 4; ++j) {
                int rl = wr * 32 + mi * 16 + lg * 4 + j;
                int row = m0 + rl;
                float xr = acc0[0][mi][ni][j] + acc1[0][mi][ni][j] * LO_INV + br;
                float xz = acc0[1][mi][ni][j] + acc1[1][mi][ni][j] * LO_INV + bz;
                float xn = acc0[2][mi][ni][j] + acc1[2][mi][ni][j] * LO_INV + bn;
                size_t grow = (size_t)row * 768;
                float hr = ghb[grow + t];
                float hz = ghb[grow + 256 + t];
                float hn = ghb[grow + 512 + t];
                float r = 1.f / (1.f + __expf(-(xr + hr)));
                float z = 1.f / (1.f + __expf(-(xz + hz)));
                float nn = tanhf(xn + r * hn);
                size_t hix = (size_t)row * 256 + t;
                T2[rl * 64 + tl] = (1.f - z) * nn + z * h[hix];
            }
        }
    }
    __syncthreads();

    // ---- pass 1: hbuf (f32) + hrm hi/lo (thread = row_local, t-quarter) ----
    {
        int rl = tid >> 2, tq = tid & 3;
        const float* src = T2 + rl * 64 + tq * 16;
        int row = m0 + rl;
        int tbase = tb * 64 + tq * 16;
        unsigned hw[8], lw[8];
#pragma unroll
        for (int e = 0; e < 8; ++e) {
            unsigned short h0, l0, h1, l1;
            splitf(src[2 * e], h0, l0);
            splitf(src[2 * e + 1], h1, l1);
            hw[e] = (unsigned)h0 | ((unsigned)h1 << 16);
            lw[e] = (unsigned)l0 | ((unsigned)l1 << 16);
        }
        float* hd = h + (size_t)row * 256 + tbase;
#pragma unroll
        for (int q = 0; q < 4; ++q)
            ((float4*)hd)[q] = *(const float4*)(src + q * 4);
        size_t ro = (size_t)row * 256 + tbase;
        ((uint4*)(hrmh + ro))[0] = (uint4){hw[0], hw[1], hw[2], hw[3]};
        ((uint4*)(hrmh + ro))[1] = (uint4){hw[4], hw[5], hw[6], hw[7]};
        ((uint4*)(hrml + ro))[0] = (uint4){lw[0], lw[1], lw[2], lw[3]};
        ((uint4*)(hrml + ro))[1] = (uint4){lw[4], lw[5], lw[6], lw[7]};
    }

    // ---- pass 2: hT hi/lo (thread = (b, t_local); rows = 4n+b) ----
    {
        int b = tid >> 6, tl = tid & 63;
        int f = b * 256 + tb * 64 + tl;
        int nbase = m0 >> 2;
        unsigned hw[8], lw[8];
#pragma unroll
        for (int e = 0; e < 8; ++e) {
            float x0 = T2[(4 * (2 * e) + b) * 64 + tl];
            float x1 = T2[(4 * (2 * e + 1) + b) * 64 + tl];
            unsigned short h0, l0, h1, l1;
            splitf(x0, h0, l0);
            splitf(x1, h1, l1);
            hw[e] = (unsigned)h0 | ((unsigned)h1 << 16);
            lw[e] = (unsigned)l0 | ((unsigned)l1 << 16);
        }
        size_t fo = (size_t)f * 2048 + nbase;
        ((uint4*)(hTh + fo))[0] = (uint4){hw[0], hw[1], hw[2], hw[3]};
        ((uint4*)(hTh + fo))[1] = (uint4){hw[4], hw[5], hw[6], hw[7]};
        ((uint4*)(hTl + fo))[0] = (uint4){lw[0], lw[1], lw[2], lw[3]};
        ((uint4*)(hTl + fo))[1] = (uint4){lw[4], lw[5], lw[6], lw[7]};
    }
}

// ---------------------------------------------------------------------------
// mm_step1f (r10, unchanged): merged adjacency + gh.
// ---------------------------------------------------------------------------
__global__ __launch_bounds__(256, 2) void mm_step1f(
    const unsigned short* __restrict__ AhHi, const unsigned short* __restrict__ AhLo,
    const unsigned short* __restrict__ AtHi, const unsigned short* __restrict__ AtLo,
    const unsigned short* __restrict__ hTh, const unsigned short* __restrict__ hTl,
    unsigned short* __restrict__ Xhi, unsigned short* __restrict__ Xlo,
    const unsigned short* __restrict__ hrmh, const unsigned short* __restrict__ hrml,
    const unsigned short* __restrict__ WhhH, const unsigned short* __restrict__ WhhL,
    const float* __restrict__ b_hh, float* __restrict__ ghb)
{
    __shared__ unsigned short LDS[16384];   // 32KB
    int tid = threadIdx.x;
    unsigned bid = blockIdx.x;
    int lane = tid & 63, r16 = lane & 15, g = lane >> 4;
    int wv = tid >> 6, wr = wv >> 1, wc = wv & 1;
    int rp = tid >> 3, sl8 = ((tid & 7) ^ (rp & 7)) * 8;

    f32x4 acc0[2][2], acc1[2][2];
#pragma unroll
    for (int mi = 0; mi < 2; ++mi)
#pragma unroll
        for (int ni = 0; ni < 2; ++ni) {
            acc0[mi][ni] = (f32x4){0.f, 0.f, 0.f, 0.f};
            acc1[mi][ni] = (f32x4){0.f, 0.f, 0.f, 0.f};
        }

    if (bid < 1024) {
        unsigned wk = (bid & 7) * 128 + (bid >> 3);
        unsigned bz = wk >> 7, rem = wk & 127, by = rem >> 2, bx = rem & 3;
        int b = bz >> 1, wio = bz & 1;
        const unsigned short* Ahp = (wio ? AtHi : AhHi) + (size_t)b * 4194304;
        const unsigned short* Alp = (wio ? AtLo : AhLo) + (size_t)b * 4194304;
        size_t boff = (size_t)(b * 256 + bx * 64) * 2048;
        int m0 = by * 64;
        const int K = 2048;
        const unsigned short* ag0 = Ahp + (size_t)(m0 + rp) * K + sl8;
        const unsigned short* ag1 = Alp + (size_t)(m0 + rp) * K + sl8;
        const unsigned short* bg0 = hTh + boff + (size_t)rp * K + sl8;
        const unsigned short* bg1 = hTl + boff + (size_t)rp * K + sl8;

        mm_loop64f<1>(ag0, ag1, bg0, bg1, K, K, K, LDS, tid, acc0, acc1);

        float* T = reinterpret_cast<float*>(LDS);
#pragma unroll
        for (int mi = 0; mi < 2; ++mi)
#pragma unroll
            for (int ni = 0; ni < 2; ++ni)
#pragma unroll
                for (int j = 0; j < 4; ++j)
                    T[(wr * 32 + mi * 16 + g * 4 + j) * 68 +
                      wc * 32 + ni * 16 + r16] =
                        acc0[mi][ni][j] + acc1[mi][ni][j] * LO_INV;
        __syncthreads();

        int row = tid >> 2, fq = tid & 3;
        const float* src = T + row * 68 + fq * 16;
        unsigned hw[8], lw[8];
#pragma unroll
        for (int e = 0; e < 8; ++e) {
            unsigned short h0, l0, h1, l1;
            splitf(src[2 * e], h0, l0);
            splitf(src[2 * e + 1], h1, l1);
            hw[e] = (unsigned)h0 | ((unsigned)h1 << 16);
            lw[e] = (unsigned)l0 | ((unsigned)l1 << 16);
        }
        size_t base = ((size_t)(m0 + row) * 4 + b) * 512 + wio * 256 + bx * 64 + fq * 16;
        ((uint4*)(Xhi + base))[0] = (uint4){hw[0], hw[1], hw[2], hw[3]};
        ((uint4*)(Xhi + base))[1] = (uint4){hw[4], hw[5], hw[6], hw[7]};
        ((uint4*)(Xlo + base))[0] = (uint4){lw[0], lw[1], lw[2], lw[3]};
        ((uint4*)(Xlo + base))[1] = (uint4){lw[4], lw[5], lw[6], lw[7]};
    } else {
        unsigned gidx = bid - 1024;
        unsigned by = gidx / 12, bx = gidx % 12;
        int m0 = by * 64, n0 = bx * 64;
        const int K = 256;
        const unsigned short* ag0 = hrmh + (size_t)(m0 + rp) * K + sl8;
        const unsigned short* ag1 = hrml + (size_t)(m0 + rp) * K + sl8;
        const unsigned short* bg0 = WhhH + (size_t)(n0 + rp) * K + sl8;
        const unsigned short* bg1 = WhhL + (size_t)(n0 + rp) * K + sl8;

        mm_loop64f<1>(ag0, ag1, bg0, bg1, K, K, K, LDS, tid, acc0, acc1);

#pragma unroll
        for (int mi = 0; mi < 2; ++mi) {
#pragma unroll
            for (int ni = 0; ni < 2; ++ni) {
                int col = n0 + wc * 32 + ni * 16 + r16;
                float badd = b_hh[col];
#pragma unroll
                for (int j = 0; j < 4; ++j) {
                    int row = m0 + wr * 32 + mi * 16 + g * 4 + j;
                    ghb[(size_t)row * 768 + col] =
                        acc0[mi][ni][j] + acc1[mi][ni][j] * LO_INV + badd;
                }
            }
        }
    }
}

// ---------------------------------------------------------------------------
// fp16 split / cast helpers (tier-1)
// ---------------------------------------------------------------------------
__global__ void split_adj16(const float* __restrict__ adj,
                            unsigned short* __restrict__ nhi, unsigned short* __restrict__ nlo,
                            unsigned short* __restrict__ thi, unsigned short* __restrict__ tlo)
{
    __shared__ float t[64][68];
    int z = blockIdx.z;
    const float* src = adj + (size_t)z * 4194304;
    int tx = threadIdx.x & 15, ty = threadIdx.x >> 4;
    int i0 = blockIdx.y * 64, j0 = blockIdx.x * 64;
#pragma unroll
    for (int i = 0; i < 4; ++i) {
        int r = ty * 4 + i;
        float4 v = *(const float4*)(src + (size_t)(i0 + r) * 2048 + j0 + tx * 4);
        ushort4 h, l;
        splitf(v.x, h.x, l.x); splitf(v.y, h.y, l.y);
        splitf(v.z, h.z, l.z); splitf(v.w, h.w, l.w);
        size_t o = (size_t)z * 4194304 + (size_t)(i0 + r) * 2048 + j0 + tx * 4;
        *(ushort4*)(nhi + o) = h; *(ushort4*)(nlo + o) = l;
        t[r][tx * 4 + 0] = v.x; t[r][tx * 4 + 1] = v.y;
        t[r][tx * 4 + 2] = v.z; t[r][tx * 4 + 3] = v.w;
    }
    __syncthreads();
#pragma unroll
    for (int i = 0; i < 4; ++i) {
        int r = ty * 4 + i;
        ushort4 h, l;
        splitf(t[tx * 4 + 0][r], h.x, l.x);
        splitf(t[tx * 4 + 1][r], h.y, l.y);
        splitf(t[tx * 4 + 2][r], h.z, l.z);
        splitf(t[tx * 4 + 3][r], h.w, l.w);
        size_t o = (size_t)z * 4194304 + (size_t)(j0 + r) * 2048 + i0 + tx * 4;
        *(ushort4*)(thi + o) = h; *(ushort4*)(tlo + o) = l;
    }
}

// h [2048][1024] f32 -> hT hi/lo fp16 [1024][2048]; optional row-major hi/lo
// (used once before the GRU loop; steady-state splits come from gxgru)
__global__ void split_h16(const float* __restrict__ h,
                          unsigned short* __restrict__ hi, unsigned short* __restrict__ lo,
                          unsigned short* __restrict__ hrmh, unsigned short* __restrict__ hrml)
{
    __shared__ float t[64][68];
    int f0 = blockIdx.x * 64, n0 = blockIdx.y * 64;
    int tx = threadIdx.x & 15, ty = threadIdx.x >> 4;
#pragma unroll
    for (int i = 0; i < 4; ++i) {
        int r = ty * 4 + i;
        float4 v = *(const float4*)(h + (size_t)(n0 + r) * 1024 + f0 + tx * 4);
        t[r][tx * 4 + 0] = v.x; t[r][tx * 4 + 1] = v.y;
        t[r][tx * 4 + 2] = v.z; t[r][tx * 4 + 3] = v.w;
        if (hrmh) {
            ushort4 hh, ll;
            splitf(v.x, hh.x, ll.x); splitf(v.y, hh.y, ll.y);
            splitf(v.z, hh.z, ll.z); splitf(v.w, hh.w, ll.w);
            size_t o = (size_t)(n0 + r) * 1024 + f0 + tx * 4;
            *(ushort4*)(hrmh + o) = hh;
            *(ushort4*)(hrml + o) = ll;
        }
    }
    __syncthreads();
#pragma unroll
    for (int i = 0; i < 4; ++i) {
        int r = ty * 4 + i;
        ushort4 hh, ll;
        splitf(t[tx * 4 + 0][r], hh.x, ll.x);
        splitf(t[tx * 4 + 1][r], hh.y, ll.y);
        splitf(t[tx * 4 + 2][r], hh.z, ll.z);
        splitf(t[tx * 4 + 3][r], hh.w, ll.w);
        size_t o = (size_t)(f0 + r) * 2048 + n0 + tx * 4;
        *(ushort4*)(hi + o) = hh; *(ushort4*)(lo + o) = ll;
    }
}

// fp32 [R][C] -> fp16 normal [R][C] (ldN) + fp16 transposed [C][R] (ldT)
__global__ void split_t16(const float* __restrict__ in,
                          unsigned short* __restrict__ outN, int ldN,
                          unsigned short* __restrict__ outT, int ldT,
                          int R, int C)
{
    __shared__ float t[64][68];
    int i0 = blockIdx.y * 64, j0 = blockIdx.x * 64;
    int tx = threadIdx.x & 15, ty = threadIdx.x >> 4;
#pragma unroll
    for (int i = 0; i < 4; ++i) {
        int r = ty * 4 + i;
        float4 v = *(const float4*)(in + (size_t)(i0 + r) * C + j0 + tx * 4);
        ushort4 hh;
        hh.x = f16r(v.x); hh.y = f16r(v.y);
        hh.z = f16r(v.z); hh.w = f16r(v.w);
        *(ushort4*)(outN + (size_t)(i0 + r) * ldN + j0 + tx * 4) = hh;
        t[r][tx * 4 + 0] = v.x; t[r][tx * 4 + 1] = v.y;
        t[r][tx * 4 + 2] = v.z; t[r][tx * 4 + 3] = v.w;
    }
    __syncthreads();
#pragma unroll
    for (int i = 0; i < 4; ++i) {
        int r = ty * 4 + i;
        ushort4 hh;
        hh.x = f16r(t[tx * 4 + 0][r]);
        hh.y = f16r(t[tx * 4 + 1][r]);
        hh.z = f16r(t[tx * 4 + 2][r]);
        hh.w = f16r(t[tx * 4 + 3][r]);
        *(ushort4*)(outT + (size_t)(j0 + r) * ldT + i0 + tx * 4) = hh;
    }
}

// one launch: W_ih 2-term REORDERED (t-block-major) | W_hh 2-term | projW 1-term
__global__ void split_w16(const float* __restrict__ Wih, const float* __restrict__ Whh,
                          const float* __restrict__ pj,
                          unsigned short* __restrict__ WihH, unsigned short* __restrict__ WihL,
                          unsigned short* __restrict__ WhhH, unsigned short* __restrict__ WhhL,
                          unsigned short* __restrict__ pjH)
{
    int i = blockIdx.x * 256 + threadIdx.x;
    if (i < 393216) {
        int row = i >> 9, col = i & 511;
        int g = row >> 8, t = row & 255;
        int nrow = (t >> 6) * 192 + g * 64 + (t & 63);
        unsigned short h, l;
        splitf(Wih[i], h, l);
        WihH[nrow * 512 + col] = h; WihL[nrow * 512 + col] = l;
    } else if (i < 589824) {
        int j = i - 393216;
        unsigned short h, l;
        splitf(Whh[j], h, l);
        WhhH[j] = h; WhhL[j] = l;
    } else if (i < 655360) {
        int j = i - 589824;
        pjH[j] = f16r(pj[j]);
    }
}

// ---------------------------------------------------------------------------
// generic fp32 GEMM + bf16 fallback kernels (tiers 2/3, unchanged)
// ---------------------------------------------------------------------------
__global__ __launch_bounds__(256, 2) void gemm_f32(
    const float* __restrict__ A, const float* __restrict__ B, float* __restrict__ C,
    int M, int N, int K, int lda, int ldb, int ldc,
    long sA, long sB, long sC,
    const float* __restrict__ bias, int ta, int tb, int accum)
{
    int bz = blockIdx.z;
    int taEff = ta;
    if (ta == 2) {
        int b = bz >> 1, w = bz & 1;
        A += (long)b * sA; B += (long)b * sB; C += (long)b * sC + w * 256;
        taEff = w;
    } else {
        A += (long)bz * sA; B += (long)bz * sB; C += (long)bz * sC;
    }
    int m0 = blockIdx.y * BM, n0 = blockIdx.x * BN;

    __shared__ float As[BK][BM + 4];
    __shared__ float Bs[BK][BN + 4];

    int tid = threadIdx.x;
    int tx = tid & 15, ty = tid >> 4;

    float acc[64];
#pragma unroll
    for (int i = 0; i < 64; ++i) acc[i] = 0.f;

    for (int k0 = 0; k0 < K; k0 += BK) {
        if (!taEff) {
            int m = tid >> 1, kk = (tid & 1) * 8;
            const float* src = A + (long)(m0 + m) * lda + (k0 + kk);
            float4 v0 = *(const float4*)(src);
            float4 v1 = *(const float4*)(src + 4);
            As[kk + 0][m] = v0.x; As[kk + 1][m] = v0.y;
            As[kk + 2][m] = v0.z; As[kk + 3][m] = v0.w;
            As[kk + 4][m] = v1.x; As[kk + 5][m] = v1.y;
            As[kk + 6][m] = v1.z; As[kk + 7][m] = v1.w;
        } else {
            int k = tid >> 4, mm = (tid & 15) * 8;
            const float* src = A + (long)(k0 + k) * lda + (m0 + mm);
            *(float4*)&As[k][mm]     = *(const float4*)(src);
            *(float4*)&As[k][mm + 4] = *(const float4*)(src + 4);
        }
        if (!tb) {
            int k = tid >> 4, nn = (tid & 15) * 8;
            const float* src = B + (long)(k0 + k) * ldb + (n0 + nn);
            *(float4*)&Bs[k][nn]     = *(const float4*)(src);
            *(float4*)&Bs[k][nn + 4] = *(const float4*)(src + 4);
        } else {
            int n = tid >> 1, kk = (tid & 1) * 8;
            const float* src = B + (long)(n0 + n) * ldb + (k0 + kk);
            float4 v0 = *(const float4*)(src);
            float4 v1 = *(const float4*)(src + 4);
            Bs[kk + 0][n] = v0.x; Bs[kk + 1][n] = v0.y;
            Bs[kk + 2][n] = v0.z; Bs[kk + 3][n] = v0.w;
            Bs[kk + 4][n] = v1.x; Bs[kk + 5][n] = v1.y;
            Bs[kk + 6][n] = v1.z; Bs[kk + 7][n] = v1.w;
        }
        __syncthreads();

#pragma unroll
        for (int k = 0; k < BK; ++k) {
            float a[8], b[8];
            *(float4*)&a[0] = *(const float4*)&As[k][ty * 4];
            *(float4*)&a[4] = *(const float4*)&As[k][64 + ty * 4];
            *(float4*)&b[0] = *(const float4*)&Bs[k][tx * 4];
            *(float4*)&b[4] = *(const float4*)&Bs[k][64 + tx * 4];
#pragma unroll
            for (int i = 0; i < 8; ++i)
#pragma unroll
                for (int j = 0; j < 8; ++j)
                    acc[i * 8 + j] += a[i] * b[j];
        }
        __syncthreads();
    }

#pragma unroll
    for (int i = 0; i < 8; ++i) {
        int row = m0 + ((i >> 2) ? 64 : 0) + ty * 4 + (i & 3);
#pragma unroll
        for (int jh = 0; jh < 2; ++jh) {
            int col = n0 + jh * 64 + tx * 4;
            float4 v;
            v.x = acc[i * 8 + jh * 4 + 0];
            v.y = acc[i * 8 + jh * 4 + 1];
            v.z = acc[i * 8 + jh * 4 + 2];
            v.w = acc[i * 8 + jh * 4 + 3];
            if (bias) {
                v.x += bias[col + 0]; v.y += bias[col + 1];
                v.z += bias[col + 2]; v.w += bias[col + 3];
            }
            float* dst = C + (long)row * ldc + col;
            if (accum) {
                float4 o = *(const float4*)dst;
                v.x += o.x; v.y += o.y; v.z += o.z; v.w += o.w;
            }
            *(float4*)dst = v;
        }
    }
}

__global__ void split_adj(const float* __restrict__ adj,
                          unsigned short* __restrict__ nhi, unsigned short* __restrict__ nlo,
                          unsigned short* __restrict__ thi, unsigned short* __restrict__ tlo)
{
    __shared__ float t[64][68];
    int z = blockIdx.z;
    const float* src = adj + (size_t)z * 4194304;
    int tx = threadIdx.x & 15, ty = threadIdx.x >> 4;
    int i0 = blockIdx.y * 64, j0 = blockIdx.x * 64;
#pragma unroll
    for (int i = 0; i < 4; ++i) {
        int r = ty * 4 + i;
        float4 v = *(const float4*)(src + (size_t)(i0 + r) * 2048 + j0 + tx * 4);
        ushort4 h, l;
        split2(v.x, h.x, l.x); split2(v.y, h.y, l.y);
        split2(v.z, h.z, l.z); split2(v.w, h.w, l.w);
        size_t o = (size_t)z * 4194304 + (size_t)(i0 + r) * 2048 + j0 + tx * 4;
        *(ushort4*)(nhi + o) = h; *(ushort4*)(nlo + o) = l;
        t[r][tx * 4 + 0] = v.x; t[r][tx * 4 + 1] = v.y;
        t[r][tx * 4 + 2] = v.z; t[r][tx * 4 + 3] = v.w;
    }
    __syncthreads();
#pragma unroll
    for (int i = 0; i < 4; ++i) {
        int r = ty * 4 + i;
        ushort4 h, l;
        split2(t[tx * 4 + 0][r], h.x, l.x);
        split2(t[tx * 4 + 1][r], h.y, l.y);
        split2(t[tx * 4 + 2][r], h.z, l.z);
        split2(t[tx * 4 + 3][r], h.w, l.w);
        size_t o = (size_t)z * 4194304 + (size_t)(j0 + r) * 2048 + i0 + tx * 4;
        *(ushort4*)(thi + o) = h; *(ushort4*)(tlo + o) = l;
    }
}

__global__ void split_h(const float* __restrict__ h,
                        unsigned short* __restrict__ hi, unsigned short* __restrict__ lo)
{
    __shared__ float t[64][68];
    int f0 = blockIdx.x * 64, n0 = blockIdx.y * 64;
    int tx = threadIdx.x & 15, ty = threadIdx.x >> 4;
#pragma unroll
    for (int i = 0; i < 4; ++i) {
        int r = ty * 4 + i;
        float4 v = *(const float4*)(h + (size_t)(n0 + r) * 1024 + f0 + tx * 4);
        t[r][tx * 4 + 0] = v.x; t[r][tx * 4 + 1] = v.y;
        t[r][tx * 4 + 2] = v.z; t[r][tx * 4 + 3] = v.w;
    }
    __syncthreads();
#pragma unroll
    for (int i = 0; i < 4; ++i) {
        int r = ty * 4 + i;
        ushort4 hh, ll;
        split2(t[tx * 4 + 0][r], hh.x, ll.x);
        split2(t[tx * 4 + 1][r], hh.y, ll.y);
        split2(t[tx * 4 + 2][r], hh.z, ll.z);
        split2(t[tx * 4 + 3][r], hh.w, ll.w);
        size_t o = (size_t)(f0 + r) * 2048 + n0 + tx * 4;
        *(ushort4*)(hi + o) = hh; *(ushort4*)(lo + o) = ll;
    }
}

__global__ __launch_bounds__(256, 3) void adj_mfma(
    const unsigned short* __restrict__ AhHi, const unsigned short* __restrict__ AhLo,
    const unsigned short* __restrict__ AtHi, const unsigned short* __restrict__ AtLo,
    const unsigned short* __restrict__ hTHi, const unsigned short* __restrict__ hTLo,
    float* __restrict__ c0, float* __restrict__ c1, float* __restrict__ c2)
{
    __shared__ unsigned short As[8192];
    __shared__ unsigned short Bs[8192];
    int tid = threadIdx.x;
    int bz = blockIdx.z;
    int region = bz >> 3, bw = bz & 7, b = bw >> 1, w = bw & 1;
    const unsigned short* Abase =
        (region == 2) ? (w ? AtLo : AhLo) : (w ? AtHi : AhHi);
    Abase += (size_t)b * 4194304;
    const unsigned short* Bbase = (region == 1) ? hTLo : hTHi;
    float* Cb = (region == 0) ? c0 : (region == 1 ? c1 : c2);

    int m0 = blockIdx.y * 128;
    int f0 = b * 256 + blockIdx.x * 128;

    int rp = tid >> 3;
    int sl = (tid & 7) ^ (rp & 7);
    const unsigned short* ag = Abase + (size_t)(m0 + rp) * 2048 + sl * 8;
    const unsigned short* bg = Bbase + (size_t)(f0 + rp) * 2048 + sl * 8;
    unsigned short* al = &As[(tid >> 6) * 512];
    unsigned short* bl = &Bs[(tid >> 6) * 512];

    int lane = tid & 63, r16 = lane & 15, g = lane >> 4;
    int wv = tid >> 6, wr = wv >> 1, wc = wv & 1;
    int s7 = r16 & 7;
    int t0 = (g ^ s7) * 16, t1 = ((4 + g) ^ s7) * 16;
    int arow = (wr * 64 + r16) * 128;
    int brow = (wc * 64 + r16) * 128;

    f32x4 acc[4][4];
#pragma unroll
    for (int mi = 0; mi < 4; ++mi)
#pragma unroll
        for (int ni = 0; ni < 4; ++ni)
            acc[mi][ni] = (f32x4){0.f, 0.f, 0.f, 0.f};

    for (int k0 = 0; k0 < 2048; k0 += 64) {
#pragma unroll
        for (int i = 0; i < 4; ++i)
            gload_lds16(ag + k0 + (size_t)i * 65536, al + i * 2048);
#pragma unroll
        for (int i = 0; i < 4; ++i)
            gload_lds16(bg + k0 + (size_t)i * 65536, bl + i * 2048);
        __syncthreads();

#pragma unroll
        for (int ks = 0; ks < 2; ++ks) {
            int tt = ks ? t1 : t0;
            bf16x8 af[4], bf[4];
#pragma unroll
            for (int mi = 0; mi < 4; ++mi)
                af[mi] = *(const bf16x8*)((const char*)As + arow + mi * 2048 + tt);
#pragma unroll
            for (int ni = 0; ni < 4; ++ni)
                bf[ni] = *(const bf16x8*)((const char*)Bs + brow + ni * 2048 + tt);
#pragma unroll
            for (int mi = 0; mi < 4; ++mi)
#pragma unroll
                for (int ni = 0; ni < 4; ++ni)
                    acc[mi][ni] = __builtin_amdgcn_mfma_f32_16x16x32_bf16(
                        af[mi], bf[ni], acc[mi][ni], 0, 0, 0);
        }
        __syncthreads();
    }

    int cbase = b * 512 + w * 256 + blockIdx.x * 128 + wc * 64;
#pragma unroll
    for (int mi = 0; mi < 4; ++mi) {
        int row = m0 + wr * 64 + mi * 16 + g * 4;
#pragma unroll
        for (int ni = 0; ni < 4; ++ni) {
            int col = cbase + ni * 16 + r16;
            float* dst = Cb + (size_t)row * 2048 + col;
#pragma unroll
            for (int j = 0; j < 4; ++j) dst[(size_t)j * 2048] = acc[mi][ni][j];
        }
    }
}

__global__ void reduce3(float4* __restrict__ x, const float4* __restrict__ p,
                        const float4* __restrict__ q)
{
    int i = blockIdx.x * 256 + threadIdx.x;
    float4 a = x[i], b = p[i], c = q[i];
    a.x += b.x + c.x; a.y += b.y + c.y; a.z += b.z + c.z; a.w += b.w + c.w;
    x[i] = a;
}

// ---------------------------------------------------------------------------
// elementwise kernels
// ---------------------------------------------------------------------------
__global__ void init_h(const float* __restrict__ attr, const float* __restrict__ W_i,
                       const float* __restrict__ b_i, float* __restrict__ h)
{
    int n = blockIdx.x, b = blockIdx.y, t = threadIdx.x;
    float a = attr[b * 2048 + n];
    h[(long)n * 1024 + b * 256 + t] = fmaxf(a * W_i[t] + b_i[t], 0.f);
}

__global__ void gru_ew(const float* __restrict__ gx, const float* __restrict__ gh,
                       float* __restrict__ h)
{
    int n = blockIdx.x, b = blockIdx.y, t = threadIdx.x;
    long row = ((long)n * 4 + b) * 768;
    float xr = gx[row + t], xz = gx[row + 256 + t], xn = gx[row + 512 + t];
    float hr = gh[row + t], hz = gh[row + 256 + t], hn = gh[row + 512 + t];
    float r = 1.f / (1.f + __expf(-(xr + hr)));
    float z = 1.f / (1.f + __expf(-(xz + hz)));
    float nn = tanhf(xn + r * hn);
    long hi = (long)n * 1024 + b * 256 + t;
    float ho = h[hi];
    h[hi] = (1.f - z) * nn + z * ho;
}

// tier-1 fused: h' = h + alpha*LN(relu(dP)); out = dot(h', W_o) + b_o
__global__ void ln_out(const float* __restrict__ dP, const float* __restrict__ gamma,
                       const float* __restrict__ beta, const float* __restrict__ araw,
                       const float* __restrict__ h, const float* __restrict__ W_o,
                       const float* __restrict__ b_o, float* __restrict__ out)
{
    int n = blockIdx.x, b = blockIdx.y, t = threadIdx.x;
    long row = ((long)n * 4 + b) * 256;
    float v = fmaxf(dP[row + t], 0.f);
    float s = v, s2 = v * v;
#pragma unroll
    for (int o = 1; o < 64; o <<= 1) { s += __shfl_xor(s, o); s2 += __shfl_xor(s2, o); }
    __shared__ float red[8];
    int w = t >> 6, lane = t & 63;
    if (lane == 0) { red[w] = s; red[4 + w] = s2; }
    __syncthreads();
    float S  = red[0] + red[1] + red[2] + red[3];
    float S2 = red[4] + red[5] + red[6] + red[7];
    float mu = S * (1.f / 256.f);
    float var = S2 * (1.f / 256.f) - mu * mu;
    float rs = rsqrtf(var + 1e-5f);
    float alpha = 0.2f / (1.f + __expf(-araw[0]));
    float y = h[(long)n * 1024 + b * 256 + t] +
              alpha * ((v - mu) * rs * gamma[t] + beta[t]);
    float d = y * W_o[t];
#pragma unroll
    for (int o = 1; o < 64; o <<= 1) d += __shfl_xor(d, o);
    __syncthreads();
    if (lane == 0) red[w] = d;
    __syncthreads();
    if (t == 0) out[(long)b * 2048 + n] = red[0] + red[1] + red[2] + red[3] + b_o[0];
}

// tier-2/3 epilogue kernels
__global__ void ln_residual(const float* __restrict__ dP, const float* __restrict__ gamma,
                            const float* __restrict__ beta, const float* __restrict__ araw,
                            float* __restrict__ h)
{
    int n = blockIdx.x, b = blockIdx.y, t = threadIdx.x;
    long row = ((long)n * 4 + b) * 256;
    float v = fmaxf(dP[row + t], 0.f);
    float s = v, s2 = v * v;
#pragma unroll
    for (int o = 1; o < 64; o <<= 1) { s += __shfl_xor(s, o); s2 += __shfl_xor(s2, o); }
    __shared__ float red[8];
    int w = t >> 6, lane = t & 63;
    if (lane == 0) { red[w] = s; red[4 + w] = s2; }
    __syncthreads();
    float S  = red[0] + red[1] + red[2] + red[3];
    float S2 = red[4] + red[5] + red[6] + red[7];
    float mu = S * (1.f / 256.f);
    float var = S2 * (1.f / 256.f) - mu * mu;
    float rs = rsqrtf(var + 1e-5f);
    float alpha = 0.2f / (1.f + __expf(-araw[0]));
    long hi = (long)n * 1024 + b * 256 + t;
    h[hi] += alpha * ((v - mu) * rs * gamma[t] + beta[t]);
}

__global__ void out_kernel(const float* __restrict__ h, const float* __restrict__ W_o,
                           const float* __restrict__ b_o, float* __restrict__ out)
{
    int t = threadIdx.x;
    int w = t >> 6, lane = t & 63;
    int row = blockIdx.x * 4 + w;
    int n = row >> 2, b = row & 3;
    const float* hp = h + (long)n * 1024 + b * 256;
    float s = 0.f;
#pragma unroll
    for (int i = 0; i < 4; ++i) { int c = i * 64 + lane; s += hp[c] * W_o[c]; }
#pragma unroll
    for (int o = 1; o < 64; o <<= 1) s += __shfl_xor(s, o);
    if (lane == 0) out[(long)b * 2048 + n] = s + b_o[0];
}

// ---------------------------------------------------------------------------
extern "C" void kernel_launch(void* const* d_in, const int* in_sizes, int n_in,
                              void* d_out, int out_size, void* d_ws, size_t ws_size,
                              hipStream_t stream)
{
    (void)in_sizes; (void)n_in; (void)out_size;
    const float* attr  = (const float*)d_in[0];
    const float* adj   = (const float*)d_in[1];
    const float* W_i   = (const float*)d_in[2];
    const float* b_i   = (const float*)d_in[3];
    const float* W_ih  = (const float*)d_in[4];
    const float* b_ih  = (const float*)d_in[5];
    const float* W_hh  = (const float*)d_in[6];
    const float* b_hh  = (const float*)d_in[7];
    const float* W_o   = (const float*)d_in[8];
    const float* b_o   = (const float*)d_in[9];
    const float* B1    = (const float*)d_in[10];
    const float* B2    = (const float*)d_in[11];
    const float* projW = (const float*)d_in[12];
    const float* gamma = (const float*)d_in[13];
    const float* beta  = (const float*)d_in[14];
    const float* araw  = (const float*)d_in[15];
    float* out = (float*)d_out;

    char* wsb = (char*)d_ws;
    dim3 blk(256);

    const size_t REQ1 = 0xD400000;   // tier-1 (212 MB)
    const size_t REQ2 = 0xD000000;   // tier-2 (round-2 path)

    if (ws_size >= REQ1) {
        // ---------------- tier 1 (fp16) ----------------
        float* hbuf = (float*)(wsb);                                // 8MB
        unsigned short* hrmh = (unsigned short*)(wsb + 0x0800000);  // 4MB
        unsigned short* hrml = (unsigned short*)(wsb + 0x0C00000);  // 4MB
        unsigned short* hTh  = (unsigned short*)(wsb + 0x1800000);  // 4MB
        unsigned short* hTl  = (unsigned short*)(wsb + 0x1C00000);  // 4MB
        float* ghb  = (float*)(wsb + 0x2000000);                    // 24MB f32
        unsigned short* Xhi = (unsigned short*)(wsb + 0x3800000);   // 8MB
        unsigned short* Xlo = (unsigned short*)(wsb + 0x4000000);   // 8MB
        unsigned short* Wih_h = (unsigned short*)(wsb + 0x5000000); // 768KB
        unsigned short* Wih_l = (unsigned short*)(wsb + 0x50C0000); // 768KB
        unsigned short* Whh_h = (unsigned short*)(wsb + 0x5240000); // 384KB
        unsigned short* Whh_l = (unsigned short*)(wsb + 0x52A0000); // 384KB
        unsigned short* pjh   = (unsigned short*)(wsb + 0x5300000); // 128KB
        char* R1 = wsb + 0x5400000;                                 // 128MB
        unsigned short* AhHi = (unsigned short*)(R1);
        unsigned short* AhLo = (unsigned short*)(R1 + 0x2000000);
        unsigned short* AtHi = (unsigned short*)(R1 + 0x4000000);
        unsigned short* AtLo = (unsigned short*)(R1 + 0x6000000);
        // topo aliases (after GRU loop, adjacency splits dead)
        unsigned short* B1h  = (unsigned short*)(R1);               // [2048][4096]
        unsigned short* B2T  = (unsigned short*)(R1 + 0x1000000);   // [1024][4096]
        unsigned short* uTb  = (unsigned short*)(R1 + 0x1800000);   // [1024][4096]
        unsigned short* prT  = (unsigned short*)(R1 + 0x2000000);   // [1024][3072]
        unsigned short* qTb  = (unsigned short*)(R1 + 0x2600000);   // [1024][4096]
        unsigned short* Bcat = (unsigned short*)(R1 + 0x2E00000);   // [4096][3072]
        unsigned short* dHb  = (unsigned short*)(wsb + 0x1800000);  // 4MB (hT dead)
        float* dPb = ghb;                                           // [8192][256]

        init_h<<<dim3(2048, 4), blk, 0, stream>>>(attr, W_i, b_i, hbuf);
        split_adj16<<<dim3(32, 32, 4), blk, 0, stream>>>(adj, AhHi, AhLo, AtHi, AtLo);
        split_w16<<<dim3(2560), blk, 0, stream>>>(W_ih, W_hh, projW,
            Wih_h, Wih_l, Whh_h, Whh_l, pjh);
        // initial split (steady-state splits come from gxgru epilogue)
        split_h16<<<dim3(16, 32), blk, 0, stream>>>(hbuf, hTh, hTl, hrmh, hrml);

        for (int step = 0; step < 5; ++step) {
            // merged adjacency (->X 2-term fp16) + gh (3P -> ghb)
            mm_step1f<<<dim3(2560), blk, 0, stream>>>(
                AhHi, AhLo, AtHi, AtLo, hTh, hTl, Xhi, Xlo,
                hrmh, hrml, Whh_h, Whh_l, b_hh, ghb);
            // fused gx GEMM + GRU + h split outputs
            gxgru<<<dim3(4, 128), blk, 0, stream>>>(
                Xhi, Xlo, Wih_h, Wih_l, b_ih, ghb, hbuf,
                hrmh, hrml, hTh, hTl);
        }

        // topo (fp16 1-term chain; behind LN * alpha=0.024)
        // Bcat = [B1^T | B2] : cols 0:2048 = B1^T, cols 2048:3072 = B2
        split_t16<<<dim3(64, 32), blk, 0, stream>>>(B1, B1h, 4096, Bcat, 3072,
                                                    2048, 4096);
        split_t16<<<dim3(16, 64), blk, 0, stream>>>(B2, Bcat + 2048, 3072, B2T, 4096,
                                                    4096, 1024);
        mm_f16<0, 1><<<dim3(64, 16), blk, 0, stream>>>(      // uT = hT*B1
            hTh, nullptr, 2048, Bcat, nullptr, 3072,
            2048, nullptr, nullptr, uTb, 4096);
        mm_f16<0, 1><<<dim3(32, 16), blk, 0, stream>>>(      // pT -> prT[:, :2048]
            uTb, nullptr, 4096, B1h, nullptr, 4096,
            4096, nullptr, nullptr, prT, 3072);
        mm_f16<0, 1><<<dim3(16, 16), blk, 0, stream>>>(      // rT -> prT[:, 2048:]
            uTb, nullptr, 4096, B2T, nullptr, 4096,
            4096, nullptr, nullptr, prT + 2048, 3072);
        mm_f16<0, 1><<<dim3(64, 16), blk, 0, stream>>>(      // qT = prT * Bcat^T
            prT, nullptr, 3072, Bcat, nullptr, 3072,
            3072, nullptr, nullptr, qTb, 4096);
        mm_f16<0, 1><<<dim3(16, 32), blk, 0, stream>>>(      // dH = B1*q
            B1h, nullptr, 4096, qTb, nullptr, 4096,
            4096, nullptr, nullptr, dHb, 1024);
        mm_f16<0, 0><<<dim3(4, 128), blk, 0, stream>>>(      // dP = dH*projW^T
            dHb, nullptr, 256, pjh, nullptr, 256,
            256, nullptr, nullptr, dPb, 256);

        ln_out<<<dim3(2048, 4), blk, 0, stream>>>(dPb, gamma, beta, araw,
                                                  hbuf, W_o, b_o, out);
        return;
    }

    // ---------------- tiers 2/3 (round-2 layout, bf16/fp32) ----------------
    float* hbuf = (float*)(wsb);
    float* xbuf = (float*)(wsb + 0x800000);
    float* gxb  = (float*)(wsb + 0x1800000);
    float* ghb  = (float*)(wsb + 0x3000000);
    unsigned short* AhHi = (unsigned short*)(wsb + 0x4800000);
    unsigned short* AhLo = (unsigned short*)(wsb + 0x6800000);
    unsigned short* AtHi = (unsigned short*)(wsb + 0x8800000);
    unsigned short* AtLo = (unsigned short*)(wsb + 0xA800000);
    unsigned short* hTHi = (unsigned short*)(wsb + 0xC800000);
    unsigned short* hTLo = (unsigned short*)(wsb + 0xCC00000);

    float* ub  = xbuf;
    float* pb  = gxb;
    float* qb  = gxb + (1 << 21);
    float* rb  = ghb;
    float* dHr = ghb + (1 << 20);
    float* dPb = ghb + 3 * (1 << 20);

    bool mfma_path = (ws_size >= REQ2);

    init_h<<<dim3(2048, 4), blk, 0, stream>>>(attr, W_i, b_i, hbuf);

    if (mfma_path)
        split_adj<<<dim3(32, 32, 4), blk, 0, stream>>>(adj, AhHi, AhLo, AtHi, AtLo);

    for (int step = 0; step < 5; ++step) {
        if (mfma_path) {
            split_h<<<dim3(16, 32), blk, 0, stream>>>(hbuf, hTHi, hTLo);
            adj_mfma<<<dim3(2, 16, 24), blk, 0, stream>>>(
                AhHi, AhLo, AtHi, AtLo, hTHi, hTLo, xbuf, gxb, ghb);
            reduce3<<<dim3(4096), blk, 0, stream>>>(
                (float4*)xbuf, (const float4*)gxb, (const float4*)ghb);
        } else {
            gemm_f32<<<dim3(2, 16, 8), blk, 0, stream>>>(
                adj, hbuf, xbuf, 2048, 256, 2048, 2048, 1024, 2048,
                (long)2048 * 2048, 256, 512, nullptr, 2, 0, 0);
        }
        gemm_f32<<<dim3(6, 64, 1), blk, 0, stream>>>(
            xbuf, W_ih, gxb, 8192, 768, 512, 512, 512, 768,
            0, 0, 0, b_ih, 0, 1, 0);
        gemm_f32<<<dim3(6, 64, 1), blk, 0, stream>>>(
            hbuf, W_hh, ghb, 8192, 768, 256, 256, 256, 768,
            0, 0, 0, b_hh, 0, 1, 0);
        gru_ew<<<dim3(2048, 4), blk, 0, stream>>>(gxb, ghb, hbuf);
    }

    gemm_f32<<<dim3(8, 32, 1), blk, 0, stream>>>(
        B1, hbuf, ub, 4096, 1024, 2048, 4096, 1024, 1024, 0, 0, 0, nullptr, 1, 0, 0);
    gemm_f32<<<dim3(8, 16, 1), blk, 0, stream>>>(
        B1, ub, pb, 2048, 1024, 4096, 4096, 1024, 1024, 0, 0, 0, nullptr, 0, 0, 0);
    gemm_f32<<<dim3(8, 32, 1), blk, 0, stream>>>(
        B1, pb, qb, 4096, 1024, 2048, 4096, 1024, 1024, 0, 0, 0, nullptr, 1, 0, 0);
    gemm_f32<<<dim3(8, 8, 1), blk, 0, stream>>>(
        B2, ub, rb, 1024, 1024, 4096, 1024, 1024, 1024, 0, 0, 0, nullptr, 1, 0, 0);
    gemm_f32<<<dim3(8, 32, 1), blk, 0, stream>>>(
        B2, rb, qb, 4096, 1024, 1024, 1024, 1024, 1024, 0, 0, 0, nullptr, 0, 0, 1);
    gemm_f32<<<dim3(8, 16, 1), blk, 0, stream>>>(
        B1, qb, dHr, 2048, 1024, 4096, 4096, 1024, 1024, 0, 0, 0, nullptr, 0, 0, 0);
    gemm_f32<<<dim3(2, 64, 1), blk, 0, stream>>>(
        dHr, projW, dPb, 8192, 256, 256, 256, 256, 256, 0, 0, 0, nullptr, 0, 1, 0);

    ln_residual<<<dim3(2048, 4), blk, 0, stream>>>(dPb, gamma, beta, araw, hbuf);
    out_kernel<<<dim3(2048), blk, 0, stream>>>(hbuf, W_o, b_o, out);
}

// Round 13
// 744.794 us; speedup vs baseline: 1.0549x; 1.0549x over previous
//
#include <hip/hip_runtime.h>
#include <hip/hip_fp16.h>

// ---------------------------------------------------------------------------
// GGNNWithTopoAlpha  (B=4, N=2048, HD=256, E=4096, T=1024, 5 propag steps)
// Round 13: fix r12's regression — gxgru's LDS bounce tile was stride-64
// (32-way bank conflict on pass-1 reads); pad to stride 68 (4-way, ~free).
// Also merge topo pT+rT into ONE GEMM (B1h|B2T are contiguous in ws).
// All GEMM math identical to r11/r12 (absmax should stay 0.015625).
// ---------------------------------------------------------------------------

typedef __bf16 bf16x8 __attribute__((ext_vector_type(8)));
typedef _Float16 f16x8 __attribute__((ext_vector_type(8)));
typedef float f32x4 __attribute__((ext_vector_type(4)));

#define BM 128
#define BN 128
#define BK 16
#define LO_INV (1.f / 1024.f)

// ---- bf16 helpers (tier-2/3 fallback kernels only) ----
__device__ __forceinline__ unsigned short bf16rne(float x)
{
    unsigned u = __float_as_uint(x);
    return (unsigned short)((u + 0x7FFFu + ((u >> 16) & 1u)) >> 16);
}
__device__ __forceinline__ float bf2f(unsigned short h)
{
    return __uint_as_float((unsigned)h << 16);
}
__device__ __forceinline__ void split2(float x, unsigned short& hi, unsigned short& lo)
{
    hi = bf16rne(x);
    lo = bf16rne(x - bf2f(hi));
}

// ---- fp16 helpers (tier-1) ----
__device__ __forceinline__ unsigned short f16r(float x)
{
    return __half_as_ushort(__float2half(x));
}
__device__ __forceinline__ float f16f(unsigned short u)
{
    return __half2float(__ushort_as_half(u));
}
// 2-term fp16 split, lo pre-scaled by 2^10 (keeps residuals in normal range)
__device__ __forceinline__ void splitf(float x, unsigned short& hi, unsigned short& lo)
{
    hi = f16r(x);
    lo = f16r((x - f16f(hi)) * 1024.f);
}

__device__ __forceinline__ void gload_lds16(const unsigned short* g, unsigned short* l)
{
    __builtin_amdgcn_global_load_lds(
        (const __attribute__((address_space(1))) void*)g,
        (__attribute__((address_space(3))) void*)l, 16, 0, 0);
}

// ---------------------------------------------------------------------------
// 64x64 fp16 MFMA core: BK=64, 4 waves 2x2, XOR-swizzled LDS.
// SPLIT=0: C = Ah*Bh.  SPLIT=1: acc0 = Ah*Bh; acc1 = Al*Bh + Ah*Bl (lo x2^10).
// ld = row stride (elements) of the operand matrices.
// ---------------------------------------------------------------------------
__device__ __forceinline__ void stage2(const unsigned short* g, unsigned short* l, int ld)
{
    gload_lds16(g, l);
    gload_lds16(g + (size_t)32 * ld, l + 2048);
}

template<int SPLIT>
__device__ __forceinline__ void mm_loop64f(
    const unsigned short* ag0, const unsigned short* ag1,
    const unsigned short* bg0, const unsigned short* bg1,
    int K, int lda, int ldb, unsigned short* LDS, int tid,
    f32x4 (&acc0)[2][2], f32x4 (&acc1)[2][2])
{
    constexpr int NT = SPLIT ? 2 : 1;
    constexpr int TSZ = 4096;

    int lane = tid & 63, r16 = lane & 15, g = lane >> 4, s7 = r16 & 7;
    int wv = tid >> 6, wr = wv >> 1, wc = wv & 1;
    int arow = (wr * 32 + r16) * 128;
    int brow = (wc * 32 + r16) * 128;
    unsigned short* lA = LDS + (tid >> 6) * 512;
    unsigned short* lB = LDS + NT * TSZ + (tid >> 6) * 512;
    const char* Ab = (const char*)LDS;
    const char* Bb = (const char*)(LDS + NT * TSZ);

    for (int k0 = 0; k0 < K; k0 += 64) {
        stage2(ag0 + k0, lA, lda);
        if constexpr (SPLIT) stage2(ag1 + k0, lA + TSZ, lda);
        stage2(bg0 + k0, lB, ldb);
        if constexpr (SPLIT) stage2(bg1 + k0, lB + TSZ, ldb);
        __syncthreads();
#pragma unroll
        for (int ks = 0; ks < 2; ++ks) {
            int tt = ((ks * 4 + g) ^ s7) * 16;
            f16x8 a0[2], a1[2], b0[2], b1[2];
#pragma unroll
            for (int mi = 0; mi < 2; ++mi) {
                a0[mi] = *(const f16x8*)(Ab + arow + mi * 2048 + tt);
                if constexpr (SPLIT)
                    a1[mi] = *(const f16x8*)(Ab + TSZ * 2 + arow + mi * 2048 + tt);
            }
#pragma unroll
            for (int ni = 0; ni < 2; ++ni) {
                b0[ni] = *(const f16x8*)(Bb + brow + ni * 2048 + tt);
                if constexpr (SPLIT)
                    b1[ni] = *(const f16x8*)(Bb + TSZ * 2 + brow + ni * 2048 + tt);
            }
#pragma unroll
            for (int mi = 0; mi < 2; ++mi)
#pragma unroll
                for (int ni = 0; ni < 2; ++ni) {
                    if constexpr (SPLIT) {
                        acc1[mi][ni] = __builtin_amdgcn_mfma_f32_16x16x32_f16(
                            a1[mi], b0[ni], acc1[mi][ni], 0, 0, 0);
                        acc1[mi][ni] = __builtin_amdgcn_mfma_f32_16x16x32_f16(
                            a0[mi], b1[ni], acc1[mi][ni], 0, 0, 0);
                    }
                    acc0[mi][ni] = __builtin_amdgcn_mfma_f32_16x16x32_f16(
                        a0[mi], b0[ni], acc0[mi][ni], 0, 0, 0);
                }
        }
        __syncthreads();
    }
}

// Generic fp16 wrapper: 64x64 tiles + XCD-chunked swizzle; lda/ldb row strides.
template<int SPLIT, int OF16>
__global__ __launch_bounds__(256, 2) void mm_f16(
    const unsigned short* __restrict__ Ah, const unsigned short* __restrict__ Al,
    int lda,
    const unsigned short* __restrict__ Bh, const unsigned short* __restrict__ Bl,
    int ldb,
    int K, const float* __restrict__ bias, const float* __restrict__ Cacc,
    void* __restrict__ Cout, int ldc)
{
    constexpr int NT = SPLIT ? 2 : 1;
    __shared__ unsigned short LDS[2 * NT * 4096];
    int tid = threadIdx.x;

    unsigned nwg = gridDim.x * gridDim.y;
    unsigned lin = blockIdx.y * gridDim.x + blockIdx.x;
    unsigned wk = ((nwg & 7) == 0) ? (lin & 7) * (nwg >> 3) + (lin >> 3) : lin;
    unsigned bx = wk % gridDim.x, by = wk / gridDim.x;

    int m0 = by * 64, n0 = bx * 64;
    int rp = tid >> 3, sl8 = ((tid & 7) ^ (rp & 7)) * 8;
    const unsigned short* ag0 = Ah + (size_t)(m0 + rp) * lda + sl8;
    const unsigned short* ag1 = SPLIT ? Al + (size_t)(m0 + rp) * lda + sl8 : nullptr;
    const unsigned short* bg0 = Bh + (size_t)(n0 + rp) * ldb + sl8;
    const unsigned short* bg1 = SPLIT ? Bl + (size_t)(n0 + rp) * ldb + sl8 : nullptr;

    f32x4 acc0[2][2], acc1[2][2];
#pragma unroll
    for (int mi = 0; mi < 2; ++mi)
#pragma unroll
        for (int ni = 0; ni < 2; ++ni) {
            acc0[mi][ni] = (f32x4){0.f, 0.f, 0.f, 0.f};
            acc1[mi][ni] = (f32x4){0.f, 0.f, 0.f, 0.f};
        }

    mm_loop64f<SPLIT>(ag0, ag1, bg0, bg1, K, lda, ldb, LDS, tid, acc0, acc1);

    int lane = tid & 63, r16 = lane & 15, g = lane >> 4;
    int wv = tid >> 6, wr = wv >> 1, wc = wv & 1;
#pragma unroll
    for (int mi = 0; mi < 2; ++mi) {
#pragma unroll
        for (int ni = 0; ni < 2; ++ni) {
            int col = n0 + wc * 32 + ni * 16 + r16;
            float badd = bias ? bias[col] : 0.f;
#pragma unroll
            for (int j = 0; j < 4; ++j) {
                int row = m0 + wr * 32 + mi * 16 + g * 4 + j;
                float v = acc0[mi][ni][j] + badd;
                if (SPLIT) v += acc1[mi][ni][j] * LO_INV;
                if (Cacc) v += Cacc[(size_t)row * ldc + col];
                if (OF16)
                    ((unsigned short*)Cout)[(size_t)row * ldc + col] = f16r(v);
                else
                    ((float*)Cout)[(size_t)row * ldc + col] = v;
            }
        }
    }
}

// ---------------------------------------------------------------------------
// gxgru: fused gx GEMM (3P fp16, K=512) + GRU epilogue + h split outputs.
// W_ih pre-reordered t-block-major. After GRU math, h tile bounces through
// LDS (STRIDE 68 — r12 used 64 -> 32-way bank conflict) and emits hbuf,
// hrm hi/lo, hT hi/lo. grid (4, 128) = 512 blocks. XCD-chunked swizzle.
// ---------------------------------------------------------------------------
__global__ __launch_bounds__(256, 2) void gxgru(
    const unsigned short* __restrict__ Xhi, const unsigned short* __restrict__ Xlo,
    const unsigned short* __restrict__ WihH, const unsigned short* __restrict__ WihL,
    const float* __restrict__ b_ih, const float* __restrict__ ghb,
    float* __restrict__ h,
    unsigned short* __restrict__ hrmh, unsigned short* __restrict__ hrml,
    unsigned short* __restrict__ hTh, unsigned short* __restrict__ hTl)
{
    __shared__ unsigned short LDS[34816];   // 68KB: GEMM staging 64KB | T2 64x68 f32
    int tid = threadIdx.x;

    unsigned lin = blockIdx.y * 4 + blockIdx.x;
    unsigned wk = (lin & 7) * 64 + (lin >> 3);
    unsigned tb = wk & 3, by = wk >> 2;

    int m0 = by * 64;
    const int K = 512;
    int rp = tid >> 3, sl8 = ((tid & 7) ^ (rp & 7)) * 8;
    const unsigned short* ag0 = Xhi + (size_t)(m0 + rp) * K + sl8;
    const unsigned short* ag1 = Xlo + (size_t)(m0 + rp) * K + sl8;
    const unsigned short* bh0 = WihH + (size_t)(tb * 192 + rp) * K + sl8;
    const unsigned short* bl0 = WihL + (size_t)(tb * 192 + rp) * K + sl8;

    int lane = tid & 63, r16 = lane & 15, lg = lane >> 4, s7 = r16 & 7;
    int wv = tid >> 6, wr = wv >> 1, wc = wv & 1;
    int arow = (wr * 32 + r16) * 128;
    int brow = (wc * 32 + r16) * 128;
    unsigned short* lA = LDS + (tid >> 6) * 512;
    unsigned short* lB = LDS + 8192 + (tid >> 6) * 512;

    f32x4 acc0[3][2][2], acc1[3][2][2];
#pragma unroll
    for (int g = 0; g < 3; ++g)
#pragma unroll
        for (int mi = 0; mi < 2; ++mi)
#pragma unroll
            for (int ni = 0; ni < 2; ++ni) {
                acc0[g][mi][ni] = (f32x4){0.f, 0.f, 0.f, 0.f};
                acc1[g][mi][ni] = (f32x4){0.f, 0.f, 0.f, 0.f};
            }

    for (int k0 = 0; k0 < K; k0 += 64) {
        stage2(ag0 + k0, lA, K);
        stage2(ag1 + k0, lA + 4096, K);
#pragma unroll
        for (int g = 0; g < 3; ++g) {
            stage2(bh0 + (size_t)(g * 64) * K + k0, lB + g * 4096, K);
            stage2(bl0 + (size_t)(g * 64) * K + k0, lB + 12288 + g * 4096, K);
        }
        __syncthreads();
#pragma unroll
        for (int ks = 0; ks < 2; ++ks) {
            int tt = ((ks * 4 + lg) ^ s7) * 16;
            f16x8 a0[2], a1[2];
#pragma unroll
            for (int mi = 0; mi < 2; ++mi) {
                a0[mi] = *(const f16x8*)((const char*)LDS + arow + mi * 2048 + tt);
                a1[mi] = *(const f16x8*)((const char*)LDS + 8192 + arow + mi * 2048 + tt);
            }
#pragma unroll
            for (int g = 0; g < 3; ++g) {
                f16x8 b0[2], b1[2];
#pragma unroll
                for (int ni = 0; ni < 2; ++ni) {
                    b0[ni] = *(const f16x8*)((const char*)LDS + 16384 + g * 8192 +
                                             brow + ni * 2048 + tt);
                    b1[ni] = *(const f16x8*)((const char*)LDS + 40960 + g * 8192 +
                                             brow + ni * 2048 + tt);
                }
#pragma unroll
                for (int mi = 0; mi < 2; ++mi)
#pragma unroll
                    for (int ni = 0; ni < 2; ++ni) {
                        acc1[g][mi][ni] = __builtin_amdgcn_mfma_f32_16x16x32_f16(
                            a1[mi], b0[ni], acc1[g][mi][ni], 0, 0, 0);
                        acc1[g][mi][ni] = __builtin_amdgcn_mfma_f32_16x16x32_f16(
                            a0[mi], b1[ni], acc1[g][mi][ni], 0, 0, 0);
                        acc0[g][mi][ni] = __builtin_amdgcn_mfma_f32_16x16x32_f16(
                            a0[mi], b0[ni], acc0[g][mi][ni], 0, 0, 0);
                    }
            }
        }
        __syncthreads();
    }

    // ---- GRU epilogue -> LDS tile T2[64][68] (padded stride) ----
    float* T2 = reinterpret_cast<float*>(LDS);
#pragma unroll
    for (int mi = 0; mi < 2; ++mi) {
#pragma unroll
        for (int ni = 0; ni < 2; ++ni) {
            int tl = wc * 32 + ni * 16 + r16;
            int t = tb * 64 + tl;
            float br = b_ih[t], bz = b_ih[256 + t], bn = b_ih[512 + t];
#pragma unroll
            for (int j = 0; j < 4; ++j) {
                int rl = wr * 32 + mi * 16 + lg * 4 + j;
                int row = m0 + rl;
                float xr = acc0[0][mi][ni][j] + acc1[0][mi][ni][j] * LO_INV + br;
                float xz = acc0[1][mi][ni][j] + acc1[1][mi][ni][j] * LO_INV + bz;
                float xn = acc0[2][mi][ni][j] + acc1[2][mi][ni][j] * LO_INV + bn;
                size_t grow = (size_t)row * 768;
                float hr = ghb[grow + t];
                float hz = ghb[grow + 256 + t];
                float hn = ghb[grow + 512 + t];
                float r = 1.f / (1.f + __expf(-(xr + hr)));
                float z = 1.f / (1.f + __expf(-(xz + hz)));
                float nn = tanhf(xn + r * hn);
                size_t hix = (size_t)row * 256 + t;
                T2[rl * 68 + tl] = (1.f - z) * nn + z * h[hix];
            }
        }
    }
    __syncthreads();

    // ---- pass 1: hbuf (f32) + hrm hi/lo (thread = row_local, t-quarter) ----
    {
        int rl = tid >> 2, tq = tid & 3;
        const float* src = T2 + rl * 68 + tq * 16;
        int row = m0 + rl;
        int tbase = tb * 64 + tq * 16;
        unsigned hw[8], lw[8];
#pragma unroll
        for (int e = 0; e < 8; ++e) {
            unsigned short h0, l0, h1, l1;
            splitf(src[2 * e], h0, l0);
            splitf(src[2 * e + 1], h1, l1);
            hw[e] = (unsigned)h0 | ((unsigned)h1 << 16);
            lw[e] = (unsigned)l0 | ((unsigned)l1 << 16);
        }
        float* hd = h + (size_t)row * 256 + tbase;
#pragma unroll
        for (int q = 0; q < 4; ++q)
            ((float4*)hd)[q] = *(const float4*)(src + q * 4);
        size_t ro = (size_t)row * 256 + tbase;
        ((uint4*)(hrmh + ro))[0] = (uint4){hw[0], hw[1], hw[2], hw[3]};
        ((uint4*)(hrmh + ro))[1] = (uint4){hw[4], hw[5], hw[6], hw[7]};
        ((uint4*)(hrml + ro))[0] = (uint4){lw[0], lw[1], lw[2], lw[3]};
        ((uint4*)(hrml + ro))[1] = (uint4){lw[4], lw[5], lw[6], lw[7]};
    }

    // ---- pass 2: hT hi/lo (thread = (b, t_local); rows = 4n+b) ----
    {
        int b = tid >> 6, tl = tid & 63;
        int f = b * 256 + tb * 64 + tl;
        int nbase = m0 >> 2;
        unsigned hw[8], lw[8];
#pragma unroll
        for (int e = 0; e < 8; ++e) {
            float x0 = T2[(4 * (2 * e) + b) * 68 + tl];
            float x1 = T2[(4 * (2 * e + 1) + b) * 68 + tl];
            unsigned short h0, l0, h1, l1;
            splitf(x0, h0, l0);
            splitf(x1, h1, l1);
            hw[e] = (unsigned)h0 | ((unsigned)h1 << 16);
            lw[e] = (unsigned)l0 | ((unsigned)l1 << 16);
        }
        size_t fo = (size_t)f * 2048 + nbase;
        ((uint4*)(hTh + fo))[0] = (uint4){hw[0], hw[1], hw[2], hw[3]};
        ((uint4*)(hTh + fo))[1] = (uint4){hw[4], hw[5], hw[6], hw[7]};
        ((uint4*)(hTl + fo))[0] = (uint4){lw[0], lw[1], lw[2], lw[3]};
        ((uint4*)(hTl + fo))[1] = (uint4){lw[4], lw[5], lw[6], lw[7]};
    }
}

// ---------------------------------------------------------------------------
// mm_step1f (unchanged): merged adjacency + gh.
// ---------------------------------------------------------------------------
__global__ __launch_bounds__(256, 2) void mm_step1f(
    const unsigned short* __restrict__ AhHi, const unsigned short* __restrict__ AhLo,
    const unsigned short* __restrict__ AtHi, const unsigned short* __restrict__ AtLo,
    const unsigned short* __restrict__ hTh, const unsigned short* __restrict__ hTl,
    unsigned short* __restrict__ Xhi, unsigned short* __restrict__ Xlo,
    const unsigned short* __restrict__ hrmh, const unsigned short* __restrict__ hrml,
    const unsigned short* __restrict__ WhhH, const unsigned short* __restrict__ WhhL,
    const float* __restrict__ b_hh, float* __restrict__ ghb)
{
    __shared__ unsigned short LDS[16384];   // 32KB
    int tid = threadIdx.x;
    unsigned bid = blockIdx.x;
    int lane = tid & 63, r16 = lane & 15, g = lane >> 4;
    int wv = tid >> 6, wr = wv >> 1, wc = wv & 1;
    int rp = tid >> 3, sl8 = ((tid & 7) ^ (rp & 7)) * 8;

    f32x4 acc0[2][2], acc1[2][2];
#pragma unroll
    for (int mi = 0; mi < 2; ++mi)
#pragma unroll
        for (int ni = 0; ni < 2; ++ni) {
            acc0[mi][ni] = (f32x4){0.f, 0.f, 0.f, 0.f};
            acc1[mi][ni] = (f32x4){0.f, 0.f, 0.f, 0.f};
        }

    if (bid < 1024) {
        unsigned wk = (bid & 7) * 128 + (bid >> 3);
        unsigned bz = wk >> 7, rem = wk & 127, by = rem >> 2, bx = rem & 3;
        int b = bz >> 1, wio = bz & 1;
        const unsigned short* Ahp = (wio ? AtHi : AhHi) + (size_t)b * 4194304;
        const unsigned short* Alp = (wio ? AtLo : AhLo) + (size_t)b * 4194304;
        size_t boff = (size_t)(b * 256 + bx * 64) * 2048;
        int m0 = by * 64;
        const int K = 2048;
        const unsigned short* ag0 = Ahp + (size_t)(m0 + rp) * K + sl8;
        const unsigned short* ag1 = Alp + (size_t)(m0 + rp) * K + sl8;
        const unsigned short* bg0 = hTh + boff + (size_t)rp * K + sl8;
        const unsigned short* bg1 = hTl + boff + (size_t)rp * K + sl8;

        mm_loop64f<1>(ag0, ag1, bg0, bg1, K, K, K, LDS, tid, acc0, acc1);

        float* T = reinterpret_cast<float*>(LDS);
#pragma unroll
        for (int mi = 0; mi < 2; ++mi)
#pragma unroll
            for (int ni = 0; ni < 2; ++ni)
#pragma unroll
                for (int j = 0; j < 4; ++j)
                    T[(wr * 32 + mi * 16 + g * 4 + j) * 68 +
                      wc * 32 + ni * 16 + r16] =
                        acc0[mi][ni][j] + acc1[mi][ni][j] * LO_INV;
        __syncthreads();

        int row = tid >> 2, fq = tid & 3;
        const float* src = T + row * 68 + fq * 16;
        unsigned hw[8], lw[8];
#pragma unroll
        for (int e = 0; e < 8; ++e) {
            unsigned short h0, l0, h1, l1;
            splitf(src[2 * e], h0, l0);
            splitf(src[2 * e + 1], h1, l1);
            hw[e] = (unsigned)h0 | ((unsigned)h1 << 16);
            lw[e] = (unsigned)l0 | ((unsigned)l1 << 16);
        }
        size_t base = ((size_t)(m0 + row) * 4 + b) * 512 + wio * 256 + bx * 64 + fq * 16;
        ((uint4*)(Xhi + base))[0] = (uint4){hw[0], hw[1], hw[2], hw[3]};
        ((uint4*)(Xhi + base))[1] = (uint4){hw[4], hw[5], hw[6], hw[7]};
        ((uint4*)(Xlo + base))[0] = (uint4){lw[0], lw[1], lw[2], lw[3]};
        ((uint4*)(Xlo + base))[1] = (uint4){lw[4], lw[5], lw[6], lw[7]};
    } else {
        unsigned gidx = bid - 1024;
        unsigned by = gidx / 12, bx = gidx % 12;
        int m0 = by * 64, n0 = bx * 64;
        const int K = 256;
        const unsigned short* ag0 = hrmh + (size_t)(m0 + rp) * K + sl8;
        const unsigned short* ag1 = hrml + (size_t)(m0 + rp) * K + sl8;
        const unsigned short* bg0 = WhhH + (size_t)(n0 + rp) * K + sl8;
        const unsigned short* bg1 = WhhL + (size_t)(n0 + rp) * K + sl8;

        mm_loop64f<1>(ag0, ag1, bg0, bg1, K, K, K, LDS, tid, acc0, acc1);

#pragma unroll
        for (int mi = 0; mi < 2; ++mi) {
#pragma unroll
            for (int ni = 0; ni < 2; ++ni) {
                int col = n0 + wc * 32 + ni * 16 + r16;
                float badd = b_hh[col];
#pragma unroll
                for (int j = 0; j < 4; ++j) {
                    int row = m0 + wr * 32 + mi * 16 + g * 4 + j;
                    ghb[(size_t)row * 768 + col] =
                        acc0[mi][ni][j] + acc1[mi][ni][j] * LO_INV + badd;
                }
            }
        }
    }
}

// ---------------------------------------------------------------------------
// fp16 split / cast helpers (tier-1)
// ---------------------------------------------------------------------------
__global__ void split_adj16(const float* __restrict__ adj,
                            unsigned short* __restrict__ nhi, unsigned short* __restrict__ nlo,
                            unsigned short* __restrict__ thi, unsigned short* __restrict__ tlo)
{
    __shared__ float t[64][68];
    int z = blockIdx.z;
    const float* src = adj + (size_t)z * 4194304;
    int tx = threadIdx.x & 15, ty = threadIdx.x >> 4;
    int i0 = blockIdx.y * 64, j0 = blockIdx.x * 64;
#pragma unroll
    for (int i = 0; i < 4; ++i) {
        int r = ty * 4 + i;
        float4 v = *(const float4*)(src + (size_t)(i0 + r) * 2048 + j0 + tx * 4);
        ushort4 h, l;
        splitf(v.x, h.x, l.x); splitf(v.y, h.y, l.y);
        splitf(v.z, h.z, l.z); splitf(v.w, h.w, l.w);
        size_t o = (size_t)z * 4194304 + (size_t)(i0 + r) * 2048 + j0 + tx * 4;
        *(ushort4*)(nhi + o) = h; *(ushort4*)(nlo + o) = l;
        t[r][tx * 4 + 0] = v.x; t[r][tx * 4 + 1] = v.y;
        t[r][tx * 4 + 2] = v.z; t[r][tx * 4 + 3] = v.w;
    }
    __syncthreads();
#pragma unroll
    for (int i = 0; i < 4; ++i) {
        int r = ty * 4 + i;
        ushort4 h, l;
        splitf(t[tx * 4 + 0][r], h.x, l.x);
        splitf(t[tx * 4 + 1][r], h.y, l.y);
        splitf(t[tx * 4 + 2][r], h.z, l.z);
        splitf(t[tx * 4 + 3][r], h.w, l.w);
        size_t o = (size_t)z * 4194304 + (size_t)(j0 + r) * 2048 + i0 + tx * 4;
        *(ushort4*)(thi + o) = h; *(ushort4*)(tlo + o) = l;
    }
}

// h [2048][1024] f32 -> hT hi/lo fp16 [1024][2048]; optional row-major hi/lo
__global__ void split_h16(const float* __restrict__ h,
                          unsigned short* __restrict__ hi, unsigned short* __restrict__ lo,
                          unsigned short* __restrict__ hrmh, unsigned short* __restrict__ hrml)
{
    __shared__ float t[64][68];
    int f0 = blockIdx.x * 64, n0 = blockIdx.y * 64;
    int tx = threadIdx.x & 15, ty = threadIdx.x >> 4;
#pragma unroll
    for (int i = 0; i < 4; ++i) {
        int r = ty * 4 + i;
        float4 v = *(const float4*)(h + (size_t)(n0 + r) * 1024 + f0 + tx * 4);
        t[r][tx * 4 + 0] = v.x; t[r][tx * 4 + 1] = v.y;
        t[r][tx * 4 + 2] = v.z; t[r][tx * 4 + 3] = v.w;
        if (hrmh) {
            ushort4 hh, ll;
            splitf(v.x, hh.x, ll.x); splitf(v.y, hh.y, ll.y);
            splitf(v.z, hh.z, ll.z); splitf(v.w, hh.w, ll.w);
            size_t o = (size_t)(n0 + r) * 1024 + f0 + tx * 4;
            *(ushort4*)(hrmh + o) = hh;
            *(ushort4*)(hrml + o) = ll;
        }
    }
    __syncthreads();
#pragma unroll
    for (int i = 0; i < 4; ++i) {
        int r = ty * 4 + i;
        ushort4 hh, ll;
        splitf(t[tx * 4 + 0][r], hh.x, ll.x);
        splitf(t[tx * 4 + 1][r], hh.y, ll.y);
        splitf(t[tx * 4 + 2][r], hh.z, ll.z);
        splitf(t[tx * 4 + 3][r], hh.w, ll.w);
        size_t o = (size_t)(f0 + r) * 2048 + n0 + tx * 4;
        *(ushort4*)(hi + o) = hh; *(ushort4*)(lo + o) = ll;
    }
}

// fp32 [R][C] -> fp16 normal [R][C] (ldN) + fp16 transposed [C][R] (ldT)
__global__ void split_t16(const float* __restrict__ in,
                          unsigned short* __restrict__ outN, int ldN,
                          unsigned short* __restrict__ outT, int ldT,
                          int R, int C)
{
    __shared__ float t[64][68];
    int i0 = blockIdx.y * 64, j0 = blockIdx.x * 64;
    int tx = threadIdx.x & 15, ty = threadIdx.x >> 4;
#pragma unroll
    for (int i = 0; i < 4; ++i) {
        int r = ty * 4 + i;
        float4 v = *(const float4*)(in + (size_t)(i0 + r) * C + j0 + tx * 4);
        ushort4 hh;
        hh.x = f16r(v.x); hh.y = f16r(v.y);
        hh.z = f16r(v.z); hh.w = f16r(v.w);
        *(ushort4*)(outN + (size_t)(i0 + r) * ldN + j0 + tx * 4) = hh;
        t[r][tx * 4 + 0] = v.x; t[r][tx * 4 + 1] = v.y;
        t[r][tx * 4 + 2] = v.z; t[r][tx * 4 + 3] = v.w;
    }
    __syncthreads();
#pragma unroll
    for (int i = 0; i < 4; ++i) {
        int r = ty * 4 + i;
        ushort4 hh;
        hh.x = f16r(t[tx * 4 + 0][r]);
        hh.y = f16r(t[tx * 4 + 1][r]);
        hh.z = f16r(t[tx * 4 + 2][r]);
        hh.w = f16r(t[tx * 4 + 3][r]);
        *(ushort4*)(outT + (size_t)(j0 + r) * ldT + i0 + tx * 4) = hh;
    }
}

// one launch: W_ih 2-term REORDERED (t-block-major) | W_hh 2-term | projW 1-term
__global__ void split_w16(const float* __restrict__ Wih, const float* __restrict__ Whh,
                          const float* __restrict__ pj,
                          unsigned short* __restrict__ WihH, unsigned short* __restrict__ WihL,
                          unsigned short* __restrict__ WhhH, unsigned short* __restrict__ WhhL,
                          unsigned short* __restrict__ pjH)
{
    int i = blockIdx.x * 256 + threadIdx.x;
    if (i < 393216) {
        int row = i >> 9, col = i & 511;
        int g = row >> 8, t = row & 255;
        int nrow = (t >> 6) * 192 + g * 64 + (t & 63);
        unsigned short h, l;
        splitf(Wih[i], h, l);
        WihH[nrow * 512 + col] = h; WihL[nrow * 512 + col] = l;
    } else if (i < 589824) {
        int j = i - 393216;
        unsigned short h, l;
        splitf(Whh[j], h, l);
        WhhH[j] = h; WhhL[j] = l;
    } else if (i < 655360) {
        int j = i - 589824;
        pjH[j] = f16r(pj[j]);
    }
}

// ---------------------------------------------------------------------------
// generic fp32 GEMM + bf16 fallback kernels (tiers 2/3, unchanged)
// ---------------------------------------------------------------------------
__global__ __launch_bounds__(256, 2) void gemm_f32(
    const float* __restrict__ A, const float* __restrict__ B, float* __restrict__ C,
    int M, int N, int K, int lda, int ldb, int ldc,
    long sA, long sB, long sC,
    const float* __restrict__ bias, int ta, int tb, int accum)
{
    int bz = blockIdx.z;
    int taEff = ta;
    if (ta == 2) {
        int b = bz >> 1, w = bz & 1;
        A += (long)b * sA; B += (long)b * sB; C += (long)b * sC + w * 256;
        taEff = w;
    } else {
        A += (long)bz * sA; B += (long)bz * sB; C += (long)bz * sC;
    }
    int m0 = blockIdx.y * BM, n0 = blockIdx.x * BN;

    __shared__ float As[BK][BM + 4];
    __shared__ float Bs[BK][BN + 4];

    int tid = threadIdx.x;
    int tx = tid & 15, ty = tid >> 4;

    float acc[64];
#pragma unroll
    for (int i = 0; i < 64; ++i) acc[i] = 0.f;

    for (int k0 = 0; k0 < K; k0 += BK) {
        if (!taEff) {
            int m = tid >> 1, kk = (tid & 1) * 8;
            const float* src = A + (long)(m0 + m) * lda + (k0 + kk);
            float4 v0 = *(const float4*)(src);
            float4 v1 = *(const float4*)(src + 4);
            As[kk + 0][m] = v0.x; As[kk + 1][m] = v0.y;
            As[kk + 2][m] = v0.z; As[kk + 3][m] = v0.w;
            As[kk + 4][m] = v1.x; As[kk + 5][m] = v1.y;
            As[kk + 6][m] = v1.z; As[kk + 7][m] = v1.w;
        } else {
            int k = tid >> 4, mm = (tid & 15) * 8;
            const float* src = A + (long)(k0 + k) * lda + (m0 + mm);
            *(float4*)&As[k][mm]     = *(const float4*)(src);
            *(float4*)&As[k][mm + 4] = *(const float4*)(src + 4);
        }
        if (!tb) {
            int k = tid >> 4, nn = (tid & 15) * 8;
            const float* src = B + (long)(k0 + k) * ldb + (n0 + nn);
            *(float4*)&Bs[k][nn]     = *(const float4*)(src);
            *(float4*)&Bs[k][nn + 4] = *(const float4*)(src + 4);
        } else {
            int n = tid >> 1, kk = (tid & 1) * 8;
            const float* src = B + (long)(n0 + n) * ldb + (k0 + kk);
            float4 v0 = *(const float4*)(src);
            float4 v1 = *(const float4*)(src + 4);
            Bs[kk + 0][n] = v0.x; Bs[kk + 1][n] = v0.y;
            Bs[kk + 2][n] = v0.z; Bs[kk + 3][n] = v0.w;
            Bs[kk + 4][n] = v1.x; Bs[kk + 5][n] = v1.y;
            Bs[kk + 6][n] = v1.z; Bs[kk + 7][n] = v1.w;
        }
        __syncthreads();

#pragma unroll
        for (int k = 0; k < BK; ++k) {
            float a[8], b[8];
            *(float4*)&a[0] = *(const float4*)&As[k][ty * 4];
            *(float4*)&a[4] = *(const float4*)&As[k][64 + ty * 4];
            *(float4*)&b[0] = *(const float4*)&Bs[k][tx * 4];
            *(float4*)&b[4] = *(const float4*)&Bs[k][64 + tx * 4];
#pragma unroll
            for (int i = 0; i < 8; ++i)
#pragma unroll
                for (int j = 0; j < 8; ++j)
                    acc[i * 8 + j] += a[i] * b[j];
        }
        __syncthreads();
    }

#pragma unroll
    for (int i = 0; i < 8; ++i) {
        int row = m0 + ((i >> 2) ? 64 : 0) + ty * 4 + (i & 3);
#pragma unroll
        for (int jh = 0; jh < 2; ++jh) {
            int col = n0 + jh * 64 + tx * 4;
            float4 v;
            v.x = acc[i * 8 + jh * 4 + 0];
            v.y = acc[i * 8 + jh * 4 + 1];
            v.z = acc[i * 8 + jh * 4 + 2];
            v.w = acc[i * 8 + jh * 4 + 3];
            if (bias) {
                v.x += bias[col + 0]; v.y += bias[col + 1];
                v.z += bias[col + 2]; v.w += bias[col + 3];
            }
            float* dst = C + (long)row * ldc + col;
            if (accum) {
                float4 o = *(const float4*)dst;
                v.x += o.x; v.y += o.y; v.z += o.z; v.w += o.w;
            }
            *(float4*)dst = v;
        }
    }
}

__global__ void split_adj(const float* __restrict__ adj,
                          unsigned short* __restrict__ nhi, unsigned short* __restrict__ nlo,
                          unsigned short* __restrict__ thi, unsigned short* __restrict__ tlo)
{
    __shared__ float t[64][68];
    int z = blockIdx.z;
    const float* src = adj + (size_t)z * 4194304;
    int tx = threadIdx.x & 15, ty = threadIdx.x >> 4;
    int i0 = blockIdx.y * 64, j0 = blockIdx.x * 64;
#pragma unroll
    for (int i = 0; i < 4; ++i) {
        int r = ty * 4 + i;
        float4 v = *(const float4*)(src + (size_t)(i0 + r) * 2048 + j0 + tx * 4);
        ushort4 h, l;
        split2(v.x, h.x, l.x); split2(v.y, h.y, l.y);
        split2(v.z, h.z, l.z); split2(v.w, h.w, l.w);
        size_t o = (size_t)z * 4194304 + (size_t)(i0 + r) * 2048 + j0 + tx * 4;
        *(ushort4*)(nhi + o) = h; *(ushort4*)(nlo + o) = l;
        t[r][tx * 4 + 0] = v.x; t[r][tx * 4 + 1] = v.y;
        t[r][tx * 4 + 2] = v.z; t[r][tx * 4 + 3] = v.w;
    }
    __syncthreads();
#pragma unroll
    for (int i = 0; i < 4; ++i) {
        int r = ty * 4 + i;
        ushort4 h, l;
        split2(t[tx * 4 + 0][r], h.x, l.x);
        split2(t[tx * 4 + 1][r], h.y, l.y);
        split2(t[tx * 4 + 2][r], h.z, l.z);
        split2(t[tx * 4 + 3][r], h.w, l.w);
        size_t o = (size_t)z * 4194304 + (size_t)(j0 + r) * 2048 + i0 + tx * 4;
        *(ushort4*)(thi + o) = h; *(ushort4*)(tlo + o) = l;
    }
}

__global__ void split_h(const float* __restrict__ h,
                        unsigned short* __restrict__ hi, unsigned short* __restrict__ lo)
{
    __shared__ float t[64][68];
    int f0 = blockIdx.x * 64, n0 = blockIdx.y * 64;
    int tx = threadIdx.x & 15, ty = threadIdx.x >> 4;
#pragma unroll
    for (int i = 0; i < 4; ++i) {
        int r = ty * 4 + i;
        float4 v = *(const float4*)(h + (size_t)(n0 + r) * 1024 + f0 + tx * 4);
        t[r][tx * 4 + 0] = v.x; t[r][tx * 4 + 1] = v.y;
        t[r][tx * 4 + 2] = v.z; t[r][tx * 4 + 3] = v.w;
    }
    __syncthreads();
#pragma unroll
    for (int i = 0; i < 4; ++i) {
        int r = ty * 4 + i;
        ushort4 hh, ll;
        split2(t[tx * 4 + 0][r], hh.x, ll.x);
        split2(t[tx * 4 + 1][r], hh.y, ll.y);
        split2(t[tx * 4 + 2][r], hh.z, ll.z);
        split2(t[tx * 4 + 3][r], hh.w, ll.w);
        size_t o = (size_t)(f0 + r) * 2048 + n0 + tx * 4;
        *(ushort4*)(hi + o) = hh; *(ushort4*)(lo + o) = ll;
    }
}

__global__ __launch_bounds__(256, 3) void adj_mfma(
    const unsigned short* __restrict__ AhHi, const unsigned short* __restrict__ AhLo,
    const unsigned short* __restrict__ AtHi, const unsigned short* __restrict__ AtLo,
    const unsigned short* __restrict__ hTHi, const unsigned short* __restrict__ hTLo,
    float* __restrict__ c0, float* __restrict__ c1, float* __restrict__ c2)
{
    __shared__ unsigned short As[8192];
    __shared__ unsigned short Bs[8192];
    int tid = threadIdx.x;
    int bz = blockIdx.z;
    int region = bz >> 3, bw = bz & 7, b = bw >> 1, w = bw & 1;
    const unsigned short* Abase =
        (region == 2) ? (w ? AtLo : AhLo) : (w ? AtHi : AhHi);
    Abase += (size_t)b * 4194304;
    const unsigned short* Bbase = (region == 1) ? hTLo : hTHi;
    float* Cb = (region == 0) ? c0 : (region == 1 ? c1 : c2);

    int m0 = blockIdx.y * 128;
    int f0 = b * 256 + blockIdx.x * 128;

    int rp = tid >> 3;
    int sl = (tid & 7) ^ (rp & 7);
    const unsigned short* ag = Abase + (size_t)(m0 + rp) * 2048 + sl * 8;
    const unsigned short* bg = Bbase + (size_t)(f0 + rp) * 2048 + sl * 8;
    unsigned short* al = &As[(tid >> 6) * 512];
    unsigned short* bl = &Bs[(tid >> 6) * 512];

    int lane = tid & 63, r16 = lane & 15, g = lane >> 4;
    int wv = tid >> 6, wr = wv >> 1, wc = wv & 1;
    int s7 = r16 & 7;
    int t0 = (g ^ s7) * 16, t1 = ((4 + g) ^ s7) * 16;
    int arow = (wr * 64 + r16) * 128;
    int brow = (wc * 64 + r16) * 128;

    f32x4 acc[4][4];
#pragma unroll
    for (int mi = 0; mi < 4; ++mi)
#pragma unroll
        for (int ni = 0; ni < 4; ++ni)
            acc[mi][ni] = (f32x4){0.f, 0.f, 0.f, 0.f};

    for (int k0 = 0; k0 < 2048; k0 += 64) {
#pragma unroll
        for (int i = 0; i < 4; ++i)
            gload_lds16(ag + k0 + (size_t)i * 65536, al + i * 2048);
#pragma unroll
        for (int i = 0; i < 4; ++i)
            gload_lds16(bg + k0 + (size_t)i * 65536, bl + i * 2048);
        __syncthreads();

#pragma unroll
        for (int ks = 0; ks < 2; ++ks) {
            int tt = ks ? t1 : t0;
            bf16x8 af[4], bf[4];
#pragma unroll
            for (int mi = 0; mi < 4; ++mi)
                af[mi] = *(const bf16x8*)((const char*)As + arow + mi * 2048 + tt);
#pragma unroll
            for (int ni = 0; ni < 4; ++ni)
                bf[ni] = *(const bf16x8*)((const char*)Bs + brow + ni * 2048 + tt);
#pragma unroll
            for (int mi = 0; mi < 4; ++mi)
#pragma unroll
                for (int ni = 0; ni < 4; ++ni)
                    acc[mi][ni] = __builtin_amdgcn_mfma_f32_16x16x32_bf16(
                        af[mi], bf[ni], acc[mi][ni], 0, 0, 0);
        }
        __syncthreads();
    }

    int cbase = b * 512 + w * 256 + blockIdx.x * 128 + wc * 64;
#pragma unroll
    for (int mi = 0; mi < 4; ++mi) {
        int row = m0 + wr * 64 + mi * 16 + g * 4;
#pragma unroll
        for (int ni = 0; ni < 4; ++ni) {
            int col = cbase + ni * 16 + r16;
            float* dst = Cb + (size_t)row * 2048 + col;
#pragma unroll
            for (int j = 0; j < 4; ++j) dst[(size_t)j * 2048] = acc[mi][ni][j];
        }
    }
}

__global__ void reduce3(float4* __restrict__ x, const float4* __restrict__ p,
                        const float4* __restrict__ q)
{
    int i = blockIdx.x * 256 + threadIdx.x;
    float4 a = x[i], b = p[i], c = q[i];
    a.x += b.x + c.x; a.y += b.y + c.y; a.z += b.z + c.z; a.w += b.w + c.w;
    x[i] = a;
}

// ---------------------------------------------------------------------------
// elementwise kernels
// ---------------------------------------------------------------------------
__global__ void init_h(const float* __restrict__ attr, const float* __restrict__ W_i,
                       const float* __restrict__ b_i, float* __restrict__ h)
{
    int n = blockIdx.x, b = blockIdx.y, t = threadIdx.x;
    float a = attr[b * 2048 + n];
    h[(long)n * 1024 + b * 256 + t] = fmaxf(a * W_i[t] + b_i[t], 0.f);
}

__global__ void gru_ew(const float* __restrict__ gx, const float* __restrict__ gh,
                       float* __restrict__ h)
{
    int n = blockIdx.x, b = blockIdx.y, t = threadIdx.x;
    long row = ((long)n * 4 + b) * 768;
    float xr = gx[row + t], xz = gx[row + 256 + t], xn = gx[row + 512 + t];
    float hr = gh[row + t], hz = gh[row + 256 + t], hn = gh[row + 512 + t];
    float r = 1.f / (1.f + __expf(-(xr + hr)));
    float z = 1.f / (1.f + __expf(-(xz + hz)));
    float nn = tanhf(xn + r * hn);
    long hi = (long)n * 1024 + b * 256 + t;
    float ho = h[hi];
    h[hi] = (1.f - z) * nn + z * ho;
}

// tier-1 fused: h' = h + alpha*LN(relu(dP)); out = dot(h', W_o) + b_o
__global__ void ln_out(const float* __restrict__ dP, const float* __restrict__ gamma,
                       const float* __restrict__ beta, const float* __restrict__ araw,
                       const float* __restrict__ h, const float* __restrict__ W_o,
                       const float* __restrict__ b_o, float* __restrict__ out)
{
    int n = blockIdx.x, b = blockIdx.y, t = threadIdx.x;
    long row = ((long)n * 4 + b) * 256;
    float v = fmaxf(dP[row + t], 0.f);
    float s = v, s2 = v * v;
#pragma unroll
    for (int o = 1; o < 64; o <<= 1) { s += __shfl_xor(s, o); s2 += __shfl_xor(s2, o); }
    __shared__ float red[8];
    int w = t >> 6, lane = t & 63;
    if (lane == 0) { red[w] = s; red[4 + w] = s2; }
    __syncthreads();
    float S  = red[0] + red[1] + red[2] + red[3];
    float S2 = red[4] + red[5] + red[6] + red[7];
    float mu = S * (1.f / 256.f);
    float var = S2 * (1.f / 256.f) - mu * mu;
    float rs = rsqrtf(var + 1e-5f);
    float alpha = 0.2f / (1.f + __expf(-araw[0]));
    float y = h[(long)n * 1024 + b * 256 + t] +
              alpha * ((v - mu) * rs * gamma[t] + beta[t]);
    float d = y * W_o[t];
#pragma unroll
    for (int o = 1; o < 64; o <<= 1) d += __shfl_xor(d, o);
    __syncthreads();
    if (lane == 0) red[w] = d;
    __syncthreads();
    if (t == 0) out[(long)b * 2048 + n] = red[0] + red[1] + red[2] + red[3] + b_o[0];
}

// tier-2/3 epilogue kernels
__global__ void ln_residual(const float* __restrict__ dP, const float* __restrict__ gamma,
                            const float* __restrict__ beta, const float* __restrict__ araw,
                            float* __restrict__ h)
{
    int n = blockIdx.x, b = blockIdx.y, t = threadIdx.x;
    long row = ((long)n * 4 + b) * 256;
    float v = fmaxf(dP[row + t], 0.f);
    float s = v, s2 = v * v;
#pragma unroll
    for (int o = 1; o < 64; o <<= 1) { s += __shfl_xor(s, o); s2 += __shfl_xor(s2, o); }
    __shared__ float red[8];
    int w = t >> 6, lane = t & 63;
    if (lane == 0) { red[w] = s; red[4 + w] = s2; }
    __syncthreads();
    float S  = red[0] + red[1] + red[2] + red[3];
    float S2 = red[4] + red[5] + red[6] + red[7];
    float mu = S * (1.f / 256.f);
    float var = S2 * (1.f / 256.f) - mu * mu;
    float rs = rsqrtf(var + 1e-5f);
    float alpha = 0.2f / (1.f + __expf(-araw[0]));
    long hi = (long)n * 1024 + b * 256 + t;
    h[hi] += alpha * ((v - mu) * rs * gamma[t] + beta[t]);
}

__global__ void out_kernel(const float* __restrict__ h, const float* __restrict__ W_o,
                           const float* __restrict__ b_o, float* __restrict__ out)
{
    int t = threadIdx.x;
    int w = t >> 6, lane = t & 63;
    int row = blockIdx.x * 4 + w;
    int n = row >> 2, b = row & 3;
    const float* hp = h + (long)n * 1024 + b * 256;
    float s = 0.f;
#pragma unroll
    for (int i = 0; i < 4; ++i) { int c = i * 64 + lane; s += hp[c] * W_o[c]; }
#pragma unroll
    for (int o = 1; o < 64; o <<= 1) s += __shfl_xor(s, o);
    if (lane == 0) out[(long)b * 2048 + n] = s + b_o[0];
}

// ---------------------------------------------------------------------------
extern "C" void kernel_launch(void* const* d_in, const int* in_sizes, int n_in,
                              void* d_out, int out_size, void* d_ws, size_t ws_size,
                              hipStream_t stream)
{
    (void)in_sizes; (void)n_in; (void)out_size;
    const float* attr  = (const float*)d_in[0];
    const float* adj   = (const float*)d_in[1];
    const float* W_i   = (const float*)d_in[2];
    const float* b_i   = (const float*)d_in[3];
    const float* W_ih  = (const float*)d_in[4];
    const float* b_ih  = (const float*)d_in[5];
    const float* W_hh  = (const float*)d_in[6];
    const float* b_hh  = (const float*)d_in[7];
    const float* W_o   = (const float*)d_in[8];
    const float* b_o   = (const float*)d_in[9];
    const float* B1    = (const float*)d_in[10];
    const float* B2    = (const float*)d_in[11];
    const float* projW = (const float*)d_in[12];
    const float* gamma = (const float*)d_in[13];
    const float* beta  = (const float*)d_in[14];
    const float* araw  = (const float*)d_in[15];
    float* out = (float*)d_out;

    char* wsb = (char*)d_ws;
    dim3 blk(256);

    const size_t REQ1 = 0xD400000;   // tier-1 (212 MB)
    const size_t REQ2 = 0xD000000;   // tier-2 (round-2 path)

    if (ws_size >= REQ1) {
        // ---------------- tier 1 (fp16) ----------------
        float* hbuf = (float*)(wsb);                                // 8MB
        unsigned short* hrmh = (unsigned short*)(wsb + 0x0800000);  // 4MB
        unsigned short* hrml = (unsigned short*)(wsb + 0x0C00000);  // 4MB
        unsigned short* hTh  = (unsigned short*)(wsb + 0x1800000);  // 4MB
        unsigned short* hTl  = (unsigned short*)(wsb + 0x1C00000);  // 4MB
        float* ghb  = (float*)(wsb + 0x2000000);                    // 24MB f32
        unsigned short* Xhi = (unsigned short*)(wsb + 0x3800000);   // 8MB
        unsigned short* Xlo = (unsigned short*)(wsb + 0x4000000);   // 8MB
        unsigned short* Wih_h = (unsigned short*)(wsb + 0x5000000); // 768KB
        unsigned short* Wih_l = (unsigned short*)(wsb + 0x50C0000); // 768KB
        unsigned short* Whh_h = (unsigned short*)(wsb + 0x5240000); // 384KB
        unsigned short* Whh_l = (unsigned short*)(wsb + 0x52A0000); // 384KB
        unsigned short* pjh   = (unsigned short*)(wsb + 0x5300000); // 128KB
        char* R1 = wsb + 0x5400000;                                 // 128MB
        unsigned short* AhHi = (unsigned short*)(R1);
        unsigned short* AhLo = (unsigned short*)(R1 + 0x2000000);
        unsigned short* AtHi = (unsigned short*)(R1 + 0x4000000);
        unsigned short* AtLo = (unsigned short*)(R1 + 0x6000000);
        // topo aliases (after GRU loop, adjacency splits dead)
        // B1h [2048][4096] followed CONTIGUOUSLY by B2T [1024][4096]
        // -> stacked [3072][4096] B-operand for the merged pT/rT GEMM.
        unsigned short* B1h  = (unsigned short*)(R1);               // [2048][4096]
        unsigned short* B2T  = (unsigned short*)(R1 + 0x1000000);   // [1024][4096]
        unsigned short* uTb  = (unsigned short*)(R1 + 0x1800000);   // [1024][4096]
        unsigned short* prT  = (unsigned short*)(R1 + 0x2000000);   // [1024][3072]
        unsigned short* qTb  = (unsigned short*)(R1 + 0x2600000);   // [1024][4096]
        unsigned short* Bcat = (unsigned short*)(R1 + 0x2E00000);   // [4096][3072]
        unsigned short* dHb  = (unsigned short*)(wsb + 0x1800000);  // 4MB (hT dead)
        float* dPb = ghb;                                           // [8192][256]

        init_h<<<dim3(2048, 4), blk, 0, stream>>>(attr, W_i, b_i, hbuf);
        split_adj16<<<dim3(32, 32, 4), blk, 0, stream>>>(adj, AhHi, AhLo, AtHi, AtLo);
        split_w16<<<dim3(2560), blk, 0, stream>>>(W_ih, W_hh, projW,
            Wih_h, Wih_l, Whh_h, Whh_l, pjh);
        // initial split (steady-state splits come from gxgru epilogue)
        split_h16<<<dim3(16, 32), blk, 0, stream>>>(hbuf, hTh, hTl, hrmh, hrml);

        for (int step = 0; step < 5; ++step) {
            // merged adjacency (->X 2-term fp16) + gh (3P -> ghb)
            mm_step1f<<<dim3(2560), blk, 0, stream>>>(
                AhHi, AhLo, AtHi, AtLo, hTh, hTl, Xhi, Xlo,
                hrmh, hrml, Whh_h, Whh_l, b_hh, ghb);
            // fused gx GEMM + GRU + h split outputs (padded LDS bounce)
            gxgru<<<dim3(4, 128), blk, 0, stream>>>(
                Xhi, Xlo, Wih_h, Wih_l, b_ih, ghb, hbuf,
                hrmh, hrml, hTh, hTl);
        }

        // topo (fp16 1-term chain; behind LN * alpha=0.024)
        // Bcat = [B1^T | B2] : cols 0:2048 = B1^T, cols 2048:3072 = B2
        split_t16<<<dim3(64, 32), blk, 0, stream>>>(B1, B1h, 4096, Bcat, 3072,
                                                    2048, 4096);
        split_t16<<<dim3(16, 64), blk, 0, stream>>>(B2, Bcat + 2048, 3072, B2T, 4096,
                                                    4096, 1024);
        mm_f16<0, 1><<<dim3(64, 16), blk, 0, stream>>>(      // uT = hT*B1
            hTh, nullptr, 2048, Bcat, nullptr, 3072,
            2048, nullptr, nullptr, uTb, 4096);
        mm_f16<0, 1><<<dim3(48, 16), blk, 0, stream>>>(      // prT = uT*[B1;B2^T]^T
            uTb, nullptr, 4096, B1h, nullptr, 4096,
            4096, nullptr, nullptr, prT, 3072);
        mm_f16<0, 1><<<dim3(64, 16), blk, 0, stream>>>(      // qT = prT * Bcat^T
            prT, nullptr, 3072, Bcat, nullptr, 3072,
            3072, nullptr, nullptr, qTb, 4096);
        mm_f16<0, 1><<<dim3(16, 32), blk, 0, stream>>>(      // dH = B1*q
            B1h, nullptr, 4096, qTb, nullptr, 4096,
            4096, nullptr, nullptr, dHb, 1024);
        mm_f16<0, 0><<<dim3(4, 128), blk, 0, stream>>>(      // dP = dH*projW^T
            dHb, nullptr, 256, pjh, nullptr, 256,
            256, nullptr, nullptr, dPb, 256);

        ln_out<<<dim3(2048, 4), blk, 0, stream>>>(dPb, gamma, beta, araw,
                                                  hbuf, W_o, b_o, out);
        return;
    }

    // ---------------- tiers 2/3 (round-2 layout, bf16/fp32) ----------------
    float* hbuf = (float*)(wsb);
    float* xbuf = (float*)(wsb + 0x800000);
    float* gxb  = (float*)(wsb + 0x1800000);
    float* ghb  = (float*)(wsb + 0x3000000);
    unsigned short* AhHi = (unsigned short*)(wsb + 0x4800000);
    unsigned short* AhLo = (unsigned short*)(wsb + 0x6800000);
    unsigned short* AtHi = (unsigned short*)(wsb + 0x8800000);
    unsigned short* AtLo = (unsigned short*)(wsb + 0xA800000);
    unsigned short* hTHi = (unsigned short*)(wsb + 0xC800000);
    unsigned short* hTLo = (unsigned short*)(wsb + 0xCC00000);

    float* ub  = xbuf;
    float* pb  = gxb;
    float* qb  = gxb + (1 << 21);
    float* rb  = ghb;
    float* dHr = ghb + (1 << 20);
    float* dPb = ghb + 3 * (1 << 20);

    bool mfma_path = (ws_size >= REQ2);

    init_h<<<dim3(2048, 4), blk, 0, stream>>>(attr, W_i, b_i, hbuf);

    if (mfma_path)
        split_adj<<<dim3(32, 32, 4), blk, 0, stream>>>(adj, AhHi, AhLo, AtHi, AtLo);

    for (int step = 0; step < 5; ++step) {
        if (mfma_path) {
            split_h<<<dim3(16, 32), blk, 0, stream>>>(hbuf, hTHi, hTLo);
            adj_mfma<<<dim3(2, 16, 24), blk, 0, stream>>>(
                AhHi, AhLo, AtHi, AtLo, hTHi, hTLo, xbuf, gxb, ghb);
            reduce3<<<dim3(4096), blk, 0, stream>>>(
                (float4*)xbuf, (const float4*)gxb, (const float4*)ghb);
        } else {
            gemm_f32<<<dim3(2, 16, 8), blk, 0, stream>>>(
                adj, hbuf, xbuf, 2048, 256, 2048, 2048, 1024, 2048,
                (long)2048 * 2048, 256, 512, nullptr, 2, 0, 0);
        }
        gemm_f32<<<dim3(6, 64, 1), blk, 0, stream>>>(
            xbuf, W_ih, gxb, 8192, 768, 512, 512, 512, 768,
            0, 0, 0, b_ih, 0, 1, 0);
        gemm_f32<<<dim3(6, 64, 1), blk, 0, stream>>>(
            hbuf, W_hh, ghb, 8192, 768, 256, 256, 256, 768,
            0, 0, 0, b_hh, 0, 1, 0);
        gru_ew<<<dim3(2048, 4), blk, 0, stream>>>(gxb, ghb, hbuf);
    }

    gemm_f32<<<dim3(8, 32, 1), blk, 0, stream>>>(
        B1, hbuf, ub, 4096, 1024, 2048, 4096, 1024, 1024, 0, 0, 0, nullptr, 1, 0, 0);
    gemm_f32<<<dim3(8, 16, 1), blk, 0, stream>>>(
        B1, ub, pb, 2048, 1024, 4096, 4096, 1024, 1024, 0, 0, 0, nullptr, 0, 0, 0);
    gemm_f32<<<dim3(8, 32, 1), blk, 0, stream>>>(
        B1, pb, qb, 4096, 1024, 2048, 4096, 1024, 1024, 0, 0, 0, nullptr, 1, 0, 0);
    gemm_f32<<<dim3(8, 8, 1), blk, 0, stream>>>(
        B2, ub, rb, 1024, 1024, 4096, 1024, 1024, 1024, 0, 0, 0, nullptr, 1, 0, 0);
    gemm_f32<<<dim3(8, 32, 1), blk, 0, stream>>>(
        B2, rb, qb, 4096, 1024, 1024, 1024, 1024, 1024, 0, 0, 0, nullptr, 0, 0, 1);
    gemm_f32<<<dim3(8, 16, 1), blk, 0, stream>>>(
        B1, qb, dHr, 2048, 1024, 4096, 4096, 1024, 1024, 0, 0, 0, nullptr, 0, 0, 0);
    gemm_f32<<<dim3(2, 64, 1), blk, 0, stream>>>(
        dHr, projW, dPb, 8192, 256, 256, 256, 256, 256, 0, 0, 0, nullptr, 0, 1, 0);

    ln_residual<<<dim3(2048, 4), blk, 0, stream>>>(dPb, gamma, beta, araw, hbuf);
    out_kernel<<<dim3(2048), blk, 0, stream>>>(hbuf, W_o, b_o, out);
}